// Round 13
// baseline (1861.482 us; speedup 1.0000x reference)
//
#include <hip/hip_runtime.h>
#include <hip/hip_bf16.h>
#include <stdint.h>

typedef unsigned short u16;
typedef unsigned int   u32;
typedef __attribute__((ext_vector_type(8))) short short8;
typedef __attribute__((ext_vector_type(4))) short s16x4;
typedef __attribute__((ext_vector_type(4))) float f32x4;

// ---------- 16x16x16 bf16 MFMA: builtin if available (device pass), else inline asm ----------
__device__ __forceinline__ f32x4 mfma16(s16x4 a, s16x4 b, f32x4 c) {
#if defined(__HIP_DEVICE_COMPILE__)
#if __has_builtin(__builtin_amdgcn_mfma_f32_16x16x16bf16_1k)
  return __builtin_amdgcn_mfma_f32_16x16x16bf16_1k(a, b, c, 0, 0, 0);
#else
  asm volatile("s_nop 1\n\tv_mfma_f32_16x16x16_bf16 %0, %1, %2, %0"
               : "+v"(c) : "v"(a), "v"(b));
  return c;
#endif
#else
  return c;  // host pass: never executed
#endif
}

// ---------- bf16 helpers (storage-only bf16, f32 math) ----------
__device__ __forceinline__ float bf2f(u16 a) {
  union { u32 i; float f; } t; t.i = ((u32)a) << 16; return t.f;
}
__device__ __forceinline__ u16 f2bf(float f) {
  union { u32 i; float f; } t; t.f = f;
  u32 r = t.i + 0x7fffu + ((t.i >> 16) & 1u);   // round-nearest-even
  return (u16)(r >> 16);
}
__device__ __forceinline__ u32 pack2(float a, float b) {
  return (u32)f2bf(a) | ((u32)f2bf(b) << 16);
}
__device__ __forceinline__ void unpack8(uint4 u, float* o) {
  union { u32 i; float f; } t;
  t.i = u.x << 16;         o[0] = t.f;
  t.i = u.x & 0xffff0000u; o[1] = t.f;
  t.i = u.y << 16;         o[2] = t.f;
  t.i = u.y & 0xffff0000u; o[3] = t.f;
  t.i = u.z << 16;         o[4] = t.f;
  t.i = u.z & 0xffff0000u; o[5] = t.f;
  t.i = u.w << 16;         o[6] = t.f;
  t.i = u.w & 0xffff0000u; o[7] = t.f;
}

// async global->LDS 16B per lane; LDS dest is wave-uniform base + lane*16
__device__ __forceinline__ void gload16(const u16* g, u16* l) {
  __builtin_amdgcn_global_load_lds(
      (const __attribute__((address_space(1))) unsigned int*)g,
      (__attribute__((address_space(3))) unsigned int*)l, 16, 0, 0);
}

#define NB 4
#define NN 4600
#define FF 5
#define PP 920
#define CC 512
#define NCHUNK 58   // ceil(920/16); chunk 57 has 8 valid keys

// ---------- weight transpose + bf16: W[512][Nc] f32 -> Wt[Nc][512] bf16 ----------
__global__ __launch_bounds__(256) void wtrans(const float* __restrict__ W,
                                              u16* __restrict__ Wt, int Nc) {
  __shared__ float tile[32][33];
  const int nb = blockIdx.x * 32, kb = blockIdx.y * 32;
  const int tx = threadIdx.x & 31, ty = threadIdx.x >> 5;
  #pragma unroll
  for (int i = 0; i < 4; i++)
    tile[ty + i * 8][tx] = W[(size_t)(kb + ty + i * 8) * Nc + nb + tx];
  __syncthreads();
  #pragma unroll
  for (int i = 0; i < 4; i++)
    Wt[(size_t)(nb + ty + i * 8) * 512 + kb + tx] = f2bf(tile[tx][ty + i * 8]);
}

// ---------- A providers ----------
struct AProvX {        // x[n,b,c] f32, row r=(b,n)
  const float* x;
  __device__ __forceinline__ void ldrow16(int r, int k0, float* o) const {
    if (r >= 18400) { for (int j = 0; j < 16; j++) o[j] = 0.f; return; }
    int b = r / NN, n = r - b * NN;
    const float* s = x + ((size_t)n * NB + b) * CC + k0;
    #pragma unroll
    for (int j = 0; j < 4; j++) {
      float4 v = *(const float4*)(s + j * 4);
      o[j * 4] = v.x; o[j * 4 + 1] = v.y; o[j * 4 + 2] = v.z; o[j * 4 + 3] = v.w;
    }
  }
};
struct AProvBF {
  const u16* a; int M;
  __device__ __forceinline__ void ldrow16(int r, int k0, float* o) const {
    if (r >= M) { for (int j = 0; j < 16; j++) o[j] = 0.f; return; }
    const u16* s = a + (size_t)r * CC + k0;
    unpack8(*(const uint4*)s, o);
    unpack8(*(const uint4*)(s + 8), o + 8);
  }
};
struct AProvDiag {
  const u16* xo;
  __device__ __forceinline__ void ldrow16(int r, int k0, float* o) const {
    if (r >= 18400) { for (int j = 0; j < 16; j++) o[j] = 0.f; return; }
    int b = r / NN, n = r - b * NN;
    int f = n / PP;
    const u16* s = xo + (((size_t)b * NN + n) * FF + f) * CC + k0;
    unpack8(*(const uint4*)s, o);
    unpack8(*(const uint4*)(s + 8), o + 8);
  }
};
struct AProvMix {
  const u16* xo; const float* attn2;
  __device__ __forceinline__ void ldrow16(int r, int k0, float* o) const {
    if (r >= 18400) { for (int j = 0; j < 16; j++) o[j] = 0.f; return; }
    int h = blockIdx.x;
    int b = r / NN, s = r - b * NN;
    const float* aw = attn2 + (((size_t)b * 8 + h) * NN + s) * FF;
    float w[5];
    #pragma unroll
    for (int f = 0; f < FF; f++) w[f] = aw[f];
    #pragma unroll
    for (int j = 0; j < 16; j++) o[j] = 0.f;
    const u16* base = xo + (size_t)r * FF * CC + k0;
    #pragma unroll
    for (int f = 0; f < FF; f++) {
      float t[16];
      const u16* s2 = base + (size_t)f * CC;
      unpack8(*(const uint4*)s2, t);
      unpack8(*(const uint4*)(s2 + 8), t + 8);
      #pragma unroll
      for (int j = 0; j < 16; j++) o[j] = fmaf(w[f], t[j], o[j]);
    }
  }
};

// ---------- C sinks ----------
struct CSinkQKV {      // q,k row-major; v chunk-blocked(16) transposed:
                       // vt[((pair*58 + p/16)*512 + c)*16 + p%16]
  u16 *q, *k, *vt;
  __device__ __forceinline__ void st(int r, int c, float val) const {
    u16 hv = f2bf(val);
    if (c < 512)        q[(size_t)r * CC + c] = hv;
    else if (c < 1024)  k[(size_t)r * CC + (c - 512)] = hv;
    else {
      int b = r / NN, n = r - b * NN;
      int f = n / PP, p = n - f * PP;
      size_t idx = (((size_t)(b * FF + f) * NCHUNK + (p >> 4)) * 512 + (c - 1024)) * 16 + (p & 15);
      vt[idx] = hv;
    }
  }
};
struct CSinkQ2 {
  u16* o;
  __device__ __forceinline__ void st(int r, int c, float v) const {
    o[(size_t)r * CC + c] = f2bf(v * 0.125f);
  }
};
struct CSinkBF512 {
  u16* o;
  __device__ __forceinline__ void st(int r, int c, float v) const {
    o[(size_t)r * CC + c] = f2bf(v);
  }
};
struct CSinkProj {
  float* out; const float* bias;
  __device__ __forceinline__ void st(int r, int c, float v) const {
    int b = r / NN, rem = r - b * NN;
    int f = rem / PP, p = rem - f * PP;
    out[((size_t)p * (NB * FF) + b * FF + f) * CC + c] = v + bias[c];
  }
};

// ---------- MFMA GEMM, tile 128x128, 4 waves (2x2 of 64x64), BK=32, K=512 ----------
template<class AP, class CS>
__global__ __launch_bounds__(256) void mgemm128(AP ap, const u16* __restrict__ Bt,
                                                CS cs, int M) {
  __shared__ __align__(16) u16 Al[128][40];
  __shared__ __align__(16) u16 Bl[128][40];
  const int tid = threadIdx.x;
  const int wid = tid >> 6, lane = tid & 63;
  const int lr = lane & 15, lg = lane >> 4;
  const int wr = wid >> 1, wc = wid & 1;
  const int row0 = blockIdx.y * 128, col0 = blockIdx.x * 128;
  const int srow = tid >> 1, skh = tid & 1;
  f32x4 acc[4][4];
  #pragma unroll
  for (int i = 0; i < 4; i++)
    #pragma unroll
    for (int j = 0; j < 4; j++) acc[i][j] = (f32x4){0.f, 0.f, 0.f, 0.f};

  for (int k0 = 0; k0 < 512; k0 += 32) {
    __syncthreads();
    {
      float tmp[16];
      ap.ldrow16(row0 + srow, k0 + skh * 16, tmp);
      u16 tb[16];
      #pragma unroll
      for (int j = 0; j < 16; j++) tb[j] = f2bf(tmp[j]);
      *(uint4*)&Al[srow][skh * 16]     = *(const uint4*)&tb[0];
      *(uint4*)&Al[srow][skh * 16 + 8] = *(const uint4*)&tb[8];
    }
    {
      const u16* s = Bt + (size_t)(col0 + srow) * 512 + k0 + skh * 16;
      *(uint4*)&Bl[srow][skh * 16]     = *(const uint4*)s;
      *(uint4*)&Bl[srow][skh * 16 + 8] = *(const uint4*)(s + 8);
    }
    __syncthreads();
    short8 afr[4], bfr[4];
    #pragma unroll
    for (int mt = 0; mt < 4; mt++)
      afr[mt] = *(const short8*)&Al[wr * 64 + mt * 16 + lr][lg * 8];
    #pragma unroll
    for (int ct = 0; ct < 4; ct++)
      bfr[ct] = *(const short8*)&Bl[wc * 64 + ct * 16 + lr][lg * 8];
    #pragma unroll
    for (int mt = 0; mt < 4; mt++)
      #pragma unroll
      for (int ct = 0; ct < 4; ct++)
        acc[mt][ct] = __builtin_amdgcn_mfma_f32_16x16x32_bf16(afr[mt], bfr[ct], acc[mt][ct], 0, 0, 0);
  }
  #pragma unroll
  for (int mt = 0; mt < 4; mt++)
    #pragma unroll
    for (int ct = 0; ct < 4; ct++)
      #pragma unroll
      for (int r = 0; r < 4; r++) {
        int rr = row0 + wr * 64 + mt * 16 + lg * 4 + r;
        if (rr < M)
          cs.st(rr, col0 + wc * 64 + ct * 16 + lr, acc[mt][ct][r]);
      }
}

// ---------- MFMA GEMM, tile 128x64, 4 waves (4x1 of 32x64), BK=32 ----------
template<class AP, class CS>
__global__ __launch_bounds__(256) void mgemm64(AP ap, const u16* __restrict__ Bt,
                                               CS cs, int M) {
  __shared__ __align__(16) u16 Al[128][40];
  __shared__ __align__(16) u16 Bl[64][40];
  const int tid = threadIdx.x;
  const int wid = tid >> 6, lane = tid & 63;
  const int lr = lane & 15, lg = lane >> 4;
  const int row0 = blockIdx.y * 128, col0 = blockIdx.x * 64;
  const int srow = tid >> 1, skh = tid & 1;
  const int bcol = tid >> 2, bkq = tid & 3;
  f32x4 acc[2][4];
  #pragma unroll
  for (int i = 0; i < 2; i++)
    #pragma unroll
    for (int j = 0; j < 4; j++) acc[i][j] = (f32x4){0.f, 0.f, 0.f, 0.f};

  for (int k0 = 0; k0 < 512; k0 += 32) {
    __syncthreads();
    {
      float tmp[16];
      ap.ldrow16(row0 + srow, k0 + skh * 16, tmp);
      u16 tb[16];
      #pragma unroll
      for (int j = 0; j < 16; j++) tb[j] = f2bf(tmp[j]);
      *(uint4*)&Al[srow][skh * 16]     = *(const uint4*)&tb[0];
      *(uint4*)&Al[srow][skh * 16 + 8] = *(const uint4*)&tb[8];
    }
    {
      const u16* s = Bt + (size_t)(col0 + bcol) * 512 + k0 + bkq * 8;
      *(uint4*)&Bl[bcol][bkq * 8] = *(const uint4*)s;
    }
    __syncthreads();
    short8 afr[2], bfr[4];
    #pragma unroll
    for (int mt = 0; mt < 2; mt++)
      afr[mt] = *(const short8*)&Al[wid * 32 + mt * 16 + lr][lg * 8];
    #pragma unroll
    for (int ct = 0; ct < 4; ct++)
      bfr[ct] = *(const short8*)&Bl[ct * 16 + lr][lg * 8];
    #pragma unroll
    for (int mt = 0; mt < 2; mt++)
      #pragma unroll
      for (int ct = 0; ct < 4; ct++)
        acc[mt][ct] = __builtin_amdgcn_mfma_f32_16x16x32_bf16(afr[mt], bfr[ct], acc[mt][ct], 0, 0, 0);
  }
  #pragma unroll
  for (int mt = 0; mt < 2; mt++)
    #pragma unroll
    for (int ct = 0; ct < 4; ct++)
      #pragma unroll
      for (int r = 0; r < 4; r++) {
        int rr = row0 + wid * 32 + mt * 16 + lg * 4 + r;
        if (rr < M)
          cs.st(rr, col0 + ct * 16 + lr, acc[mt][ct][r]);
      }
}

// ---------- logits: k2 = xo @ Wk2, epilogue dot with q2 ----------
__global__ __launch_bounds__(256) void mgemm_logits(const u16* __restrict__ xo,
                                                    const u16* __restrict__ q2,
                                                    const u16* __restrict__ Wk2t,
                                                    float* __restrict__ attn2) {
  __shared__ __align__(16) u16 Al[128][40];
  __shared__ __align__(16) u16 Bl[128][40];
  const int tid = threadIdx.x;
  const int wid = tid >> 6, lane = tid & 63;
  const int lr = lane & 15, lg = lane >> 4;
  const int wr = wid >> 1, wc = wid & 1;
  const int row0 = blockIdx.y * 128, col0 = blockIdx.x * 128;
  const int srow = tid >> 1, skh = tid & 1;
  f32x4 acc[4][4];
  #pragma unroll
  for (int i = 0; i < 4; i++)
    #pragma unroll
    for (int j = 0; j < 4; j++) acc[i][j] = (f32x4){0.f, 0.f, 0.f, 0.f};

  for (int k0 = 0; k0 < 512; k0 += 32) {
    __syncthreads();
    {
      int r = row0 + srow;
      uint4 v0 = make_uint4(0,0,0,0), v1 = make_uint4(0,0,0,0);
      if (r < 92000) {
        const u16* s = xo + (size_t)r * CC + k0 + skh * 16;
        v0 = *(const uint4*)s; v1 = *(const uint4*)(s + 8);
      }
      *(uint4*)&Al[srow][skh * 16]     = v0;
      *(uint4*)&Al[srow][skh * 16 + 8] = v1;
    }
    {
      const u16* s = Wk2t + (size_t)(col0 + srow) * 512 + k0 + skh * 16;
      *(uint4*)&Bl[srow][skh * 16]     = *(const uint4*)s;
      *(uint4*)&Bl[srow][skh * 16 + 8] = *(const uint4*)(s + 8);
    }
    __syncthreads();
    short8 afr[4], bfr[4];
    #pragma unroll
    for (int mt = 0; mt < 4; mt++)
      afr[mt] = *(const short8*)&Al[wr * 64 + mt * 16 + lr][lg * 8];
    #pragma unroll
    for (int ct = 0; ct < 4; ct++)
      bfr[ct] = *(const short8*)&Bl[wc * 64 + ct * 16 + lr][lg * 8];
    #pragma unroll
    for (int mt = 0; mt < 4; mt++)
      #pragma unroll
      for (int ct = 0; ct < 4; ct++)
        acc[mt][ct] = __builtin_amdgcn_mfma_f32_16x16x32_bf16(afr[mt], bfr[ct], acc[mt][ct], 0, 0, 0);
  }
  const int head = blockIdx.x * 2 + wc;
  #pragma unroll
  for (int mt = 0; mt < 4; mt++) {
    float part[4] = {0.f, 0.f, 0.f, 0.f};
    #pragma unroll
    for (int r = 0; r < 4; r++) {
      int rr = row0 + wr * 64 + mt * 16 + lg * 4 + r;
      int rc = rr < 92000 ? rr : 91999;
      const u16* qrow = q2 + (size_t)(rc / 5) * CC + head * 64 + lr;
      #pragma unroll
      for (int ct = 0; ct < 4; ct++)
        part[r] = fmaf(acc[mt][ct][r], bf2f(qrow[ct * 16]), part[r]);
    }
    #pragma unroll
    for (int r = 0; r < 4; r++) {
      float v = part[r];
      v += __shfl_xor(v, 1);
      v += __shfl_xor(v, 2);
      v += __shfl_xor(v, 4);
      v += __shfl_xor(v, 8);
      int rr = row0 + wr * 64 + mt * 16 + lg * 4 + r;
      if (lr == 0 && rr < 92000) {
        int b = rr / (NN * FF), rem = rr - b * (NN * FF);
        int s = rem / FF, f = rem - s * FF;
        attn2[(((size_t)b * 8 + head) * NN + s) * FF + f] = v;
      }
    }
  }
}

// ---------- stage 1 (R11 structure; V read directly from global, never staged) ----------
// Block: 4 waves x 16 q = 64 q, one (b,f). Chunk = 16 keys. Pair-affinity grid.
// K LDS [16][512] dbuf (32 KB), XOR unit^=(row&7) via pre-swizzled DMA source.
// PV V-frag: contiguous 8B/lane direct from chunk-blocked vt (L2-resident).
__global__ __launch_bounds__(256, 2) void stage1_mfma8(const u16* __restrict__ qg,
                                                       const u16* __restrict__ kg,
                                                       const u16* __restrict__ vt,
                                                       u16* __restrict__ xo) {
  __shared__ __align__(16) u16 KF[2][16 * 512];   // 2 x 16 KB
  const int tid = threadIdx.x;
  const int wid = tid >> 6, lane = tid & 63;
  const int lr = lane & 15, lg = lane >> 4;
  // XCD pair-affinity remap (bijective: 1440 = 8 * 180)
  const int wgid = blockIdx.x;
  const int g = (wgid & 7) * 180 + (wgid >> 3);
  const int pair = g / 72, qt = g - pair * 72;
  const int b = pair / 5, f = pair - b * 5;
  const int q0 = qt * 64 + wid * 16;

  const u16* kbase = kg + ((size_t)b * NN + f * PP) * CC;
  const u16* vpair = vt + (size_t)pair * NCHUNK * 8192;   // [chunk][512 ch][16 keys]

  // ---- persistent Q fragments FIRST, drained, so vmcnt counts only DMA ----
  short8 qf[16];
  {
    int qrow = q0 + lr; if (qrow > NN - 1) qrow = NN - 1;
    const u16* qb = qg + ((size_t)b * NN + qrow) * CC + lg * 8;
    #pragma unroll
    for (int ck = 0; ck < 16; ck++) qf[ck] = *(const short8*)(qb + ck * 32);
  }
  asm volatile("s_waitcnt vmcnt(0)" ::: "memory");

  // ---- K staging only: 4 DMA loads per wave per chunk ----
  #define STAGE_K(buf, kk0v)                                                   \
    {                                                                          \
      const int kk0_ = (kk0v);                                                 \
      _Pragma("unroll")                                                        \
      for (int c = 0; c < 4; c++) {                                            \
        int r = wid * 4 + c;                                                   \
        int key = kk0_ + r; if (key > PP - 1) key = PP - 1;                    \
        const u16* src = kbase + (size_t)key * CC + ((lane ^ (r & 7)) * 8);    \
        gload16(src, &KF[buf][r * 512]);                                       \
      }                                                                        \
    }

  // prologue: stage chunk 0 into buffer 0
  STAGE_K(0, 0)

  f32x4 acc[32];
  #pragma unroll
  for (int j = 0; j < 32; j++) acc[j] = (f32x4){0.f, 0.f, 0.f, 0.f};
  float m = 0.f, l = 0.f;

  for (int ch = 0; ch < NCHUNK; ch++) {      // 920 = 57*16 + 8
    const int kk0 = ch * 16;
    const int nv = (ch == NCHUNK - 1) ? 8 : 16;
    const int cur = ch & 1, nxt = cur ^ 1;
    if (ch < NCHUNK - 1) {
      STAGE_K(nxt, kk0 + 16)
      // all older loads (incl. cur-chunk K DMA + consumed V) must be done;
      // only the 4 just-issued nxt-K DMAs may remain in flight.
      asm volatile("s_waitcnt vmcnt(4)" ::: "memory");
    } else {
      asm volatile("s_waitcnt vmcnt(0)" ::: "memory");
    }
    __builtin_amdgcn_s_barrier();
    __builtin_amdgcn_sched_barrier(0);
    const u16* Kb = &KF[cur][0];
    const u16* vchunk = vpair + (size_t)ch * 8192;
    // ---- QK^T: 16 MFMAs (16x16x32), split into 2 independent chains ----
    f32x4 sa = (f32x4){0.f, 0.f, 0.f, 0.f};
    f32x4 sb = (f32x4){0.f, 0.f, 0.f, 0.f};
    #pragma unroll
    for (int ck = 0; ck < 8; ck++) {
      int sl0 = ((lr * 64 + ck * 4 + lg) ^ (lr & 7)) * 8;
      int sl1 = ((lr * 64 + (ck + 8) * 4 + lg) ^ (lr & 7)) * 8;
      short8 k0 = *(const short8*)&Kb[sl0];
      short8 k1 = *(const short8*)&Kb[sl1];
      sa = __builtin_amdgcn_mfma_f32_16x16x32_bf16(k0, qf[ck], sa, 0, 0, 0);
      sb = __builtin_amdgcn_mfma_f32_16x16x32_bf16(k1, qf[ck + 8], sb, 0, 0, 0);
    }
    f32x4 s0 = sa + sb;
    // lane: S[key=lg*4+r][q=lr] in s0[r]
    float pmax = -1e30f;
    #pragma unroll
    for (int r = 0; r < 4; r++) {
      s0[r] *= 0.125f;
      if (lg * 4 + r < nv) pmax = fmaxf(pmax, s0[r]);
    }
    pmax = fmaxf(pmax, __shfl_xor(pmax, 16));
    pmax = fmaxf(pmax, __shfl_xor(pmax, 32));          // row max (per q=lr)
    if (__any(pmax - m > 8.f)) {                       // deferred rescale (rare)
      float mnew = fmaxf(m, pmax);
      float rs = __expf(m - mnew);
      float rsr[4];
      #pragma unroll
      for (int r = 0; r < 4; r++) rsr[r] = __shfl(rs, lg * 4 + r);
      #pragma unroll
      for (int j = 0; j < 32; j++)
        #pragma unroll
        for (int r = 0; r < 4; r++) acc[j][r] *= rsr[r];
      l *= rs;
      m = mnew;
    }
    // ---- P = exp(S - m), in-register A-frag for 16x16x16 ----
    float p0 = (lg * 4 + 0 < nv) ? __expf(s0[0] - m) : 0.f;
    float p1 = (lg * 4 + 1 < nv) ? __expf(s0[1] - m) : 0.f;
    float p2 = (lg * 4 + 2 < nv) ? __expf(s0[2] - m) : 0.f;
    float p3 = (lg * 4 + 3 < nv) ? __expf(s0[3] - m) : 0.f;
    float psum = p0 + p1 + p2 + p3;
    psum += __shfl_xor(psum, 16);
    psum += __shfl_xor(psum, 32);
    l += psum;
    u32 pw[2] = { pack2(p0, p1), pack2(p2, p3) };
    s16x4 pf = *(const s16x4*)pw;
    // ---- PV: 32 MFMAs (16x16x16), V-frag 8B/lane DIRECT from global ----
    // lane (lr,lg) reads V^T[ch=ct*16+lr][keys lg*4..+3]: contiguous, coalesced.
    #pragma unroll
    for (int ct = 0; ct < 32; ct++) {
      s16x4 vf = *(const s16x4*)(vchunk + (size_t)(ct * 16 + lr) * 16 + lg * 4);
      acc[ct] = mfma16(pf, vf, acc[ct]);
    }
    __builtin_amdgcn_s_barrier();            // all waves done reading cur K
  }
  // cover MFMA-write -> VALU-read hazard before epilogue (inline-asm path)
  asm volatile("s_nop 7\n\ts_nop 7" :::);
  // ---- epilogue: normalize by l, store ----
  float linv = 1.f / l;
  float li[4];
  #pragma unroll
  for (int r = 0; r < 4; r++) li[r] = __shfl(linv, lg * 4 + r);
  #pragma unroll
  for (int ct = 0; ct < 32; ct++) {
    #pragma unroll
    for (int r = 0; r < 4; r++) {
      int q = q0 + lg * 4 + r;
      if (q < NN)
        xo[((size_t)(b * NN + q) * FF + f) * CC + ct * 16 + lr] = f2bf(acc[ct][r] * li[r]);
    }
  }
  #undef STAGE_K
}

// ---------- softmax over F=5, in place on attn2 ----------
__global__ __launch_bounds__(256) void softmax_f5(float* __restrict__ a) {
  int t = blockIdx.x * 256 + threadIdx.x;
  if (t >= NB * 8 * NN) return;
  float* p = a + (size_t)t * FF;
  float l0 = p[0], l1 = p[1], l2 = p[2], l3 = p[3], l4 = p[4];
  float m = fmaxf(fmaxf(fmaxf(l0, l1), fmaxf(l2, l3)), l4);
  float e0 = __expf(l0 - m), e1 = __expf(l1 - m), e2 = __expf(l2 - m),
        e3 = __expf(l3 - m), e4 = __expf(l4 - m);
  float inv = 1.f / (e0 + e1 + e2 + e3 + e4);
  p[0] = e0 * inv; p[1] = e1 * inv; p[2] = e2 * inv; p[3] = e3 * inv; p[4] = e4 * inv;
}

// ---------- sentinel ----------
__global__ void sentinel_fill(float* o) { o[threadIdx.x] = 777.0f; }

// ---------- launcher ----------
extern "C" void kernel_launch(void* const* d_in, const int* in_sizes, int n_in,
                              void* d_out, int out_size, void* d_ws, size_t ws_size,
                              hipStream_t stream) {
  const float* x     = (const float*)d_in[0];
  const float* Wqkv  = (const float*)d_in[1];
  const float* Wq2   = (const float*)d_in[2];
  const float* Wkv2  = (const float*)d_in[3];
  const float* Wproj = (const float*)d_in[4];
  const float* bproj = (const float*)d_in[5];
  float* out   = (float*)d_out;
  float* attn2 = out + (size_t)PP * NB * FF * CC;

  char* ws = (char*)d_ws;
  const size_t SZ  = (size_t)18400 * CC * 2;            // 18.8 MB
  const size_t VT2 = (size_t)20 * NCHUNK * 8192 * 2;    // 19.0 MB (chunk-blocked V)
  const size_t XO  = (size_t)92000 * CC * 2;            // 94.2 MB
  const size_t WT  = (size_t)(1536 + 512 + 1024 + 512) * 512 * 2;  // 3.67 MB
  const size_t NEED = 2 * SZ + VT2 + XO + WT;           // ~154.6 MB
  if (ws_size < NEED) {
    sentinel_fill<<<1, 256, 0, stream>>>(out);
    return;
  }
  u16* q    = (u16*)(ws);
  u16* k    = (u16*)(ws + SZ);
  u16* vt   = (u16*)(ws + 2 * SZ);
  u16* xo   = (u16*)(ws + 2 * SZ + VT2);
  u16* wt_qkv  = (u16*)(ws + 2 * SZ + VT2 + XO);
  u16* wt_q2   = wt_qkv + (size_t)1536 * 512;
  u16* wt_kv2  = wt_q2  + (size_t)512 * 512;
  u16* wt_proj = wt_kv2 + (size_t)1024 * 512;
  u16* q2   = (u16*)(ws);            // alias q (dead after stage1)
  u16* outp = (u16*)(ws + SZ);       // alias k (dead after stage1)

  // 0) weight transpose + bf16 conversion
  wtrans<<<dim3(48, 16), 256, 0, stream>>>(Wqkv,  wt_qkv,  1536);
  wtrans<<<dim3(16, 16), 256, 0, stream>>>(Wq2,   wt_q2,   512);
  wtrans<<<dim3(32, 16), 256, 0, stream>>>(Wkv2,  wt_kv2,  1024);
  wtrans<<<dim3(16, 16), 256, 0, stream>>>(Wproj, wt_proj, 512);

  // 1) QKV projection (MFMA; v written chunk-blocked-16 transposed)
  {
    AProvX ap{x}; CSinkQKV cs{q, k, vt};
    mgemm128<<<dim3(12, 144), 256, 0, stream>>>(ap, wt_qkv, cs, 18400);
  }
  // 2) stage-1 space attention (V-direct-from-global, pair-affinity) -> xo
  stage1_mfma8<<<1440, 256, 0, stream>>>(q, k, vt, xo);
  // 3) q2 = diag(xo) @ W_q2 * scale   (overwrites q region)
  {
    AProvDiag ap{xo}; CSinkQ2 cs{q2};
    mgemm128<<<dim3(4, 144), 256, 0, stream>>>(ap, wt_q2, cs, 18400);
  }
  // 4) fused k2-GEMM + q2 dot -> raw logits into attn2 slice of d_out
  mgemm_logits<<<dim3(4, 719), 256, 0, stream>>>(xo, q2, wt_kv2, attn2);
  // 5) softmax over F in place
  softmax_f5<<<(NB * 8 * NN + 255) / 256, 256, 0, stream>>>(attn2);
  // 6) fused mix + W_v2 -> out_pre (overwrites k region); BN=64, head = blockIdx.x
  {
    AProvMix ap{xo, attn2}; CSinkBF512 cs{outp};
    mgemm64<<<dim3(8, 144), 256, 0, stream>>>(ap, wt_kv2 + (size_t)512 * 512, cs, 18400);
  }
  // 7) final projection + bias + permute to (P, B*F, C)
  {
    AProvBF ap{outp, 18400}; CSinkProj cs{out, bproj};
    mgemm128<<<dim3(4, 144), 256, 0, stream>>>(ap, wt_proj, cs, 18400);
  }
}

// Round 14
// 813.962 us; speedup vs baseline: 2.2869x; 2.2869x over previous
//
#include <hip/hip_runtime.h>
#include <hip/hip_bf16.h>
#include <stdint.h>

typedef unsigned short u16;
typedef unsigned int   u32;
typedef __attribute__((ext_vector_type(8))) short short8;
typedef __attribute__((ext_vector_type(4))) short s16x4;
typedef __attribute__((ext_vector_type(4))) float f32x4;

// ---------- 16x16x16 bf16 MFMA: builtin if available (device pass), else inline asm ----------
__device__ __forceinline__ f32x4 mfma16(s16x4 a, s16x4 b, f32x4 c) {
#if defined(__HIP_DEVICE_COMPILE__)
#if __has_builtin(__builtin_amdgcn_mfma_f32_16x16x16bf16_1k)
  return __builtin_amdgcn_mfma_f32_16x16x16bf16_1k(a, b, c, 0, 0, 0);
#else
  asm volatile("s_nop 1\n\tv_mfma_f32_16x16x16_bf16 %0, %1, %2, %0"
               : "+v"(c) : "v"(a), "v"(b));
  return c;
#endif
#else
  return c;  // host pass: never executed
#endif
}

// ---------- bf16 helpers (storage-only bf16, f32 math) ----------
__device__ __forceinline__ float bf2f(u16 a) {
  union { u32 i; float f; } t; t.i = ((u32)a) << 16; return t.f;
}
__device__ __forceinline__ u16 f2bf(float f) {
  union { u32 i; float f; } t; t.f = f;
  u32 r = t.i + 0x7fffu + ((t.i >> 16) & 1u);   // round-nearest-even
  return (u16)(r >> 16);
}
__device__ __forceinline__ u32 pack2(float a, float b) {
  return (u32)f2bf(a) | ((u32)f2bf(b) << 16);
}
__device__ __forceinline__ void unpack8(uint4 u, float* o) {
  union { u32 i; float f; } t;
  t.i = u.x << 16;         o[0] = t.f;
  t.i = u.x & 0xffff0000u; o[1] = t.f;
  t.i = u.y << 16;         o[2] = t.f;
  t.i = u.y & 0xffff0000u; o[3] = t.f;
  t.i = u.z << 16;         o[4] = t.f;
  t.i = u.z & 0xffff0000u; o[5] = t.f;
  t.i = u.w << 16;         o[6] = t.f;
  t.i = u.w & 0xffff0000u; o[7] = t.f;
}

// async global->LDS 16B per lane; LDS dest is wave-uniform base + lane*16
__device__ __forceinline__ void gload16(const u16* g, u16* l) {
  __builtin_amdgcn_global_load_lds(
      (const __attribute__((address_space(1))) unsigned int*)g,
      (__attribute__((address_space(3))) unsigned int*)l, 16, 0, 0);
}

#define NB 4
#define NN 4600
#define FF 5
#define PP 920
#define CC 512
#define NCHUNK 58   // ceil(920/16); chunk 57 has 8 valid keys

// ---------- weight transpose + bf16: W[512][Nc] f32 -> Wt[Nc][512] bf16 ----------
__global__ __launch_bounds__(256) void wtrans(const float* __restrict__ W,
                                              u16* __restrict__ Wt, int Nc) {
  __shared__ float tile[32][33];
  const int nb = blockIdx.x * 32, kb = blockIdx.y * 32;
  const int tx = threadIdx.x & 31, ty = threadIdx.x >> 5;
  #pragma unroll
  for (int i = 0; i < 4; i++)
    tile[ty + i * 8][tx] = W[(size_t)(kb + ty + i * 8) * Nc + nb + tx];
  __syncthreads();
  #pragma unroll
  for (int i = 0; i < 4; i++)
    Wt[(size_t)(nb + ty + i * 8) * 512 + kb + tx] = f2bf(tile[tx][ty + i * 8]);
}

// ---------- A providers ----------
struct AProvX {        // x[n,b,c] f32, row r=(b,n)
  static constexpr bool RAW = false;
  const float* x;
  __device__ __forceinline__ void ldrow16(int r, int k0, float* o) const {
    if (r >= 18400) { for (int j = 0; j < 16; j++) o[j] = 0.f; return; }
    int b = r / NN, n = r - b * NN;
    const float* s = x + ((size_t)n * NB + b) * CC + k0;
    #pragma unroll
    for (int j = 0; j < 4; j++) {
      float4 v = *(const float4*)(s + j * 4);
      o[j * 4] = v.x; o[j * 4 + 1] = v.y; o[j * 4 + 2] = v.z; o[j * 4 + 3] = v.w;
    }
  }
  __device__ __forceinline__ void ldraw(int, int, uint4&, uint4&) const {}
};
struct AProvBF {       // contiguous bf16 rows, stride 512
  static constexpr bool RAW = true;
  const u16* a; int M;
  __device__ __forceinline__ void ldrow16(int, int, float*) const {}
  __device__ __forceinline__ void ldraw(int r, int k0, uint4& v0, uint4& v1) const {
    if (r >= M) { v0 = make_uint4(0,0,0,0); v1 = make_uint4(0,0,0,0); return; }
    const u16* s = a + (size_t)r * CC + k0;
    v0 = *(const uint4*)s;
    v1 = *(const uint4*)(s + 8);
  }
};
struct AProvDiag {     // x_diag: row (b,n) -> xo[b,n, n/P, c]
  static constexpr bool RAW = true;
  const u16* xo;
  __device__ __forceinline__ void ldrow16(int, int, float*) const {}
  __device__ __forceinline__ void ldraw(int r, int k0, uint4& v0, uint4& v1) const {
    if (r >= 18400) { v0 = make_uint4(0,0,0,0); v1 = make_uint4(0,0,0,0); return; }
    int b = r / NN, n = r - b * NN;
    int f = n / PP;
    const u16* s = xo + (((size_t)b * NN + n) * FF + f) * CC + k0;
    v0 = *(const uint4*)s;
    v1 = *(const uint4*)(s + 8);
  }
};
struct AProvMix {      // mixed_h[r][k] = sum_f attn2[b,h,s,f] * xo[r,f,k]; h = blockIdx.x
  static constexpr bool RAW = false;
  const u16* xo; const float* attn2;
  __device__ __forceinline__ void ldrow16(int r, int k0, float* o) const {
    if (r >= 18400) { for (int j = 0; j < 16; j++) o[j] = 0.f; return; }
    int h = blockIdx.x;
    int b = r / NN, s = r - b * NN;
    const float* aw = attn2 + (((size_t)b * 8 + h) * NN + s) * FF;
    float w[5];
    #pragma unroll
    for (int f = 0; f < FF; f++) w[f] = aw[f];
    #pragma unroll
    for (int j = 0; j < 16; j++) o[j] = 0.f;
    const u16* base = xo + (size_t)r * FF * CC + k0;
    #pragma unroll
    for (int f = 0; f < FF; f++) {
      float t[16];
      const u16* s2 = base + (size_t)f * CC;
      unpack8(*(const uint4*)s2, t);
      unpack8(*(const uint4*)(s2 + 8), t + 8);
      #pragma unroll
      for (int j = 0; j < 16; j++) o[j] = fmaf(w[f], t[j], o[j]);
    }
  }
  __device__ __forceinline__ void ldraw(int, int, uint4&, uint4&) const {}
};

// ---------- C sinks ----------
struct CSinkQKV {      // q,k row-major; v chunk-blocked(16) transposed:
                       // vt[((pair*58 + p/16)*512 + c)*16 + p%16]
  u16 *q, *k, *vt;
  __device__ __forceinline__ void st(int r, int c, float val) const {
    u16 hv = f2bf(val);
    if (c < 512)        q[(size_t)r * CC + c] = hv;
    else if (c < 1024)  k[(size_t)r * CC + (c - 512)] = hv;
    else {
      int b = r / NN, n = r - b * NN;
      int f = n / PP, p = n - f * PP;
      size_t idx = (((size_t)(b * FF + f) * NCHUNK + (p >> 4)) * 512 + (c - 1024)) * 16 + (p & 15);
      vt[idx] = hv;
    }
  }
};
struct CSinkQ2 {
  u16* o;
  __device__ __forceinline__ void st(int r, int c, float v) const {
    o[(size_t)r * CC + c] = f2bf(v * 0.125f);
  }
};
struct CSinkBF512 {
  u16* o;
  __device__ __forceinline__ void st(int r, int c, float v) const {
    o[(size_t)r * CC + c] = f2bf(v);
  }
};
struct CSinkProj {
  float* out; const float* bias;
  __device__ __forceinline__ void st(int r, int c, float v) const {
    int b = r / NN, rem = r - b * NN;
    int f = rem / PP, p = rem - f * PP;
    out[((size_t)p * (NB * FF) + b * FF + f) * CC + c] = v + bias[c];
  }
};

// ---------- MFMA GEMM, tile 128x128, 4 waves (2x2 of 64x64), BK=32, K=512 ----------
template<class AP, class CS>
__global__ __launch_bounds__(256) void mgemm128(AP ap, const u16* __restrict__ Bt,
                                                CS cs, int M) {
  __shared__ __align__(16) u16 Al[128][40];
  __shared__ __align__(16) u16 Bl[128][40];
  const int tid = threadIdx.x;
  const int wid = tid >> 6, lane = tid & 63;
  const int lr = lane & 15, lg = lane >> 4;
  const int wr = wid >> 1, wc = wid & 1;
  const int row0 = blockIdx.y * 128, col0 = blockIdx.x * 128;
  const int srow = tid >> 1, skh = tid & 1;
  f32x4 acc[4][4];
  #pragma unroll
  for (int i = 0; i < 4; i++)
    #pragma unroll
    for (int j = 0; j < 4; j++) acc[i][j] = (f32x4){0.f, 0.f, 0.f, 0.f};

  for (int k0 = 0; k0 < 512; k0 += 32) {
    __syncthreads();
    if constexpr (AP::RAW) {
      uint4 v0, v1;
      ap.ldraw(row0 + srow, k0 + skh * 16, v0, v1);
      *(uint4*)&Al[srow][skh * 16]     = v0;
      *(uint4*)&Al[srow][skh * 16 + 8] = v1;
    } else {
      float tmp[16];
      ap.ldrow16(row0 + srow, k0 + skh * 16, tmp);
      u16 tb[16];
      #pragma unroll
      for (int j = 0; j < 16; j++) tb[j] = f2bf(tmp[j]);
      *(uint4*)&Al[srow][skh * 16]     = *(const uint4*)&tb[0];
      *(uint4*)&Al[srow][skh * 16 + 8] = *(const uint4*)&tb[8];
    }
    {
      const u16* s = Bt + (size_t)(col0 + srow) * 512 + k0 + skh * 16;
      *(uint4*)&Bl[srow][skh * 16]     = *(const uint4*)s;
      *(uint4*)&Bl[srow][skh * 16 + 8] = *(const uint4*)(s + 8);
    }
    __syncthreads();
    short8 afr[4], bfr[4];
    #pragma unroll
    for (int mt = 0; mt < 4; mt++)
      afr[mt] = *(const short8*)&Al[wr * 64 + mt * 16 + lr][lg * 8];
    #pragma unroll
    for (int ct = 0; ct < 4; ct++)
      bfr[ct] = *(const short8*)&Bl[wc * 64 + ct * 16 + lr][lg * 8];
    #pragma unroll
    for (int mt = 0; mt < 4; mt++)
      #pragma unroll
      for (int ct = 0; ct < 4; ct++)
        acc[mt][ct] = __builtin_amdgcn_mfma_f32_16x16x32_bf16(afr[mt], bfr[ct], acc[mt][ct], 0, 0, 0);
  }
  #pragma unroll
  for (int mt = 0; mt < 4; mt++)
    #pragma unroll
    for (int ct = 0; ct < 4; ct++)
      #pragma unroll
      for (int r = 0; r < 4; r++) {
        int rr = row0 + wr * 64 + mt * 16 + lg * 4 + r;
        if (rr < M)
          cs.st(rr, col0 + wc * 64 + ct * 16 + lr, acc[mt][ct][r]);
      }
}

// ---------- MFMA GEMM, tile 128x64, 4 waves (4x1 of 32x64), BK=32 ----------
template<class AP, class CS>
__global__ __launch_bounds__(256) void mgemm64(AP ap, const u16* __restrict__ Bt,
                                               CS cs, int M) {
  __shared__ __align__(16) u16 Al[128][40];
  __shared__ __align__(16) u16 Bl[64][40];
  const int tid = threadIdx.x;
  const int wid = tid >> 6, lane = tid & 63;
  const int lr = lane & 15, lg = lane >> 4;
  const int row0 = blockIdx.y * 128, col0 = blockIdx.x * 64;
  const int srow = tid >> 1, skh = tid & 1;
  const int bcol = tid >> 2, bkq = tid & 3;
  f32x4 acc[2][4];
  #pragma unroll
  for (int i = 0; i < 2; i++)
    #pragma unroll
    for (int j = 0; j < 4; j++) acc[i][j] = (f32x4){0.f, 0.f, 0.f, 0.f};

  for (int k0 = 0; k0 < 512; k0 += 32) {
    __syncthreads();
    if constexpr (AP::RAW) {
      uint4 v0, v1;
      ap.ldraw(row0 + srow, k0 + skh * 16, v0, v1);
      *(uint4*)&Al[srow][skh * 16]     = v0;
      *(uint4*)&Al[srow][skh * 16 + 8] = v1;
    } else {
      float tmp[16];
      ap.ldrow16(row0 + srow, k0 + skh * 16, tmp);
      u16 tb[16];
      #pragma unroll
      for (int j = 0; j < 16; j++) tb[j] = f2bf(tmp[j]);
      *(uint4*)&Al[srow][skh * 16]     = *(const uint4*)&tb[0];
      *(uint4*)&Al[srow][skh * 16 + 8] = *(const uint4*)&tb[8];
    }
    {
      const u16* s = Bt + (size_t)(col0 + bcol) * 512 + k0 + bkq * 8;
      *(uint4*)&Bl[bcol][bkq * 8] = *(const uint4*)s;
    }
    __syncthreads();
    short8 afr[2], bfr[4];
    #pragma unroll
    for (int mt = 0; mt < 2; mt++)
      afr[mt] = *(const short8*)&Al[wid * 32 + mt * 16 + lr][lg * 8];
    #pragma unroll
    for (int ct = 0; ct < 4; ct++)
      bfr[ct] = *(const short8*)&Bl[ct * 16 + lr][lg * 8];
    #pragma unroll
    for (int mt = 0; mt < 2; mt++)
      #pragma unroll
      for (int ct = 0; ct < 4; ct++)
        acc[mt][ct] = __builtin_amdgcn_mfma_f32_16x16x32_bf16(afr[mt], bfr[ct], acc[mt][ct], 0, 0, 0);
  }
  #pragma unroll
  for (int mt = 0; mt < 2; mt++)
    #pragma unroll
    for (int ct = 0; ct < 4; ct++)
      #pragma unroll
      for (int r = 0; r < 4; r++) {
        int rr = row0 + wid * 32 + mt * 16 + lg * 4 + r;
        if (rr < M)
          cs.st(rr, col0 + ct * 16 + lr, acc[mt][ct][r]);
      }
}

// ---------- logits: k2 = xo @ Wk2, epilogue dot with q2 ----------
__global__ __launch_bounds__(256) void mgemm_logits(const u16* __restrict__ xo,
                                                    const u16* __restrict__ q2,
                                                    const u16* __restrict__ Wk2t,
                                                    float* __restrict__ attn2) {
  __shared__ __align__(16) u16 Al[128][40];
  __shared__ __align__(16) u16 Bl[128][40];
  const int tid = threadIdx.x;
  const int wid = tid >> 6, lane = tid & 63;
  const int lr = lane & 15, lg = lane >> 4;
  const int wr = wid >> 1, wc = wid & 1;
  const int row0 = blockIdx.y * 128, col0 = blockIdx.x * 128;
  const int srow = tid >> 1, skh = tid & 1;
  f32x4 acc[4][4];
  #pragma unroll
  for (int i = 0; i < 4; i++)
    #pragma unroll
    for (int j = 0; j < 4; j++) acc[i][j] = (f32x4){0.f, 0.f, 0.f, 0.f};

  for (int k0 = 0; k0 < 512; k0 += 32) {
    __syncthreads();
    {
      int r = row0 + srow;
      uint4 v0 = make_uint4(0,0,0,0), v1 = make_uint4(0,0,0,0);
      if (r < 92000) {
        const u16* s = xo + (size_t)r * CC + k0 + skh * 16;
        v0 = *(const uint4*)s; v1 = *(const uint4*)(s + 8);
      }
      *(uint4*)&Al[srow][skh * 16]     = v0;
      *(uint4*)&Al[srow][skh * 16 + 8] = v1;
    }
    {
      const u16* s = Wk2t + (size_t)(col0 + srow) * 512 + k0 + skh * 16;
      *(uint4*)&Bl[srow][skh * 16]     = *(const uint4*)s;
      *(uint4*)&Bl[srow][skh * 16 + 8] = *(const uint4*)(s + 8);
    }
    __syncthreads();
    short8 afr[4], bfr[4];
    #pragma unroll
    for (int mt = 0; mt < 4; mt++)
      afr[mt] = *(const short8*)&Al[wr * 64 + mt * 16 + lr][lg * 8];
    #pragma unroll
    for (int ct = 0; ct < 4; ct++)
      bfr[ct] = *(const short8*)&Bl[wc * 64 + ct * 16 + lr][lg * 8];
    #pragma unroll
    for (int mt = 0; mt < 4; mt++)
      #pragma unroll
      for (int ct = 0; ct < 4; ct++)
        acc[mt][ct] = __builtin_amdgcn_mfma_f32_16x16x32_bf16(afr[mt], bfr[ct], acc[mt][ct], 0, 0, 0);
  }
  const int head = blockIdx.x * 2 + wc;
  #pragma unroll
  for (int mt = 0; mt < 4; mt++) {
    float part[4] = {0.f, 0.f, 0.f, 0.f};
    #pragma unroll
    for (int r = 0; r < 4; r++) {
      int rr = row0 + wr * 64 + mt * 16 + lg * 4 + r;
      int rc = rr < 92000 ? rr : 91999;
      const u16* qrow = q2 + (size_t)(rc / 5) * CC + head * 64 + lr;
      #pragma unroll
      for (int ct = 0; ct < 4; ct++)
        part[r] = fmaf(acc[mt][ct][r], bf2f(qrow[ct * 16]), part[r]);
    }
    #pragma unroll
    for (int r = 0; r < 4; r++) {
      float v = part[r];
      v += __shfl_xor(v, 1);
      v += __shfl_xor(v, 2);
      v += __shfl_xor(v, 4);
      v += __shfl_xor(v, 8);
      int rr = row0 + wr * 64 + mt * 16 + lg * 4 + r;
      if (lr == 0 && rr < 92000) {
        int b = rr / (NN * FF), rem = rr - b * (NN * FF);
        int s = rem / FF, f = rem - s * FF;
        attn2[(((size_t)b * 8 + head) * NN + s) * FF + f] = v;
      }
    }
  }
}

// ---------- stage 1 (R11 exact: 16-key chunks, dbuf DMA K+V, chunk-blocked V) ----------
__global__ __launch_bounds__(256, 2) void stage1_mfma6(const u16* __restrict__ qg,
                                                       const u16* __restrict__ kg,
                                                       const u16* __restrict__ vt,
                                                       u16* __restrict__ xo) {
  __shared__ __align__(16) u16 KF[2][16 * 512];   // 2 x 16 KB
  __shared__ __align__(16) u16 VF[2][512 * 16];   // 2 x 16 KB
  const int tid = threadIdx.x;
  const int wid = tid >> 6, lane = tid & 63;
  const int lr = lane & 15, lg = lane >> 4;
  // XCD pair-affinity remap (bijective: 1440 = 8 * 180)
  const int wgid = blockIdx.x;
  const int g = (wgid & 7) * 180 + (wgid >> 3);
  const int pair = g / 72, qt = g - pair * 72;
  const int b = pair / 5, f = pair - b * 5;
  const int q0 = qt * 64 + wid * 16;

  const u16* kbase = kg + ((size_t)b * NN + f * PP) * CC;
  const u16* vpair = vt + (size_t)pair * NCHUNK * 8192;   // chunk-blocked slabs

  // ---- persistent Q fragments FIRST, drained, so vmcnt counts only DMA ----
  short8 qf[16];
  {
    int qrow = q0 + lr; if (qrow > NN - 1) qrow = NN - 1;
    const u16* qb = qg + ((size_t)b * NN + qrow) * CC + lg * 8;
    #pragma unroll
    for (int ck = 0; ck < 16; ck++) qf[ck] = *(const short8*)(qb + ck * 32);
  }
  asm volatile("s_waitcnt vmcnt(0)" ::: "memory");

  // ---- staging helpers (4 K-loads + 4 V-loads per wave per chunk) ----
  #define STAGE_KV(buf, kk0v, ckv)                                             \
    {                                                                          \
      const int kk0_ = (kk0v);                                                 \
      const u16* vcb_ = vpair + (size_t)(ckv) * 8192;                          \
      _Pragma("unroll")                                                        \
      for (int c = 0; c < 4; c++) {                                            \
        int r = wid * 4 + c;                                                   \
        int key = kk0_ + r; if (key > PP - 1) key = PP - 1;                    \
        const u16* src = kbase + (size_t)key * CC + ((lane ^ (r & 7)) * 8);    \
        gload16(src, &KF[buf][r * 512]);                                       \
      }                                                                        \
      _Pragma("unroll")                                                        \
      for (int c = 0; c < 4; c++) {                                            \
        int j = wid * 4 + c;                                                   \
        int ulin = j * 64 + lane;                                              \
        int uc = ulin ^ ((ulin >> 3) & 3);                                     \
        gload16(vcb_ + uc * 8, &VF[buf][j * 512]);                             \
      }                                                                        \
    }

  // prologue: stage chunk 0 into buffer 0
  STAGE_KV(0, 0, 0)

  f32x4 acc[32];
  #pragma unroll
  for (int j = 0; j < 32; j++) acc[j] = (f32x4){0.f, 0.f, 0.f, 0.f};
  float m = 0.f, l = 0.f;

  // per-lane constant V-read base (u16 index)
  const int vrd = (((2 * lr + (lg >> 1)) ^ (lr >> 2)) * 8) + (lg & 1) * 4;

  for (int ch = 0; ch < NCHUNK; ch++) {      // 920 = 57*16 + 8
    const int kk0 = ch * 16;
    const int nv = (ch == NCHUNK - 1) ? 8 : 16;
    const int cur = ch & 1, nxt = cur ^ 1;
    if (ch < NCHUNK - 1) {
      STAGE_KV(nxt, kk0 + 16, ch + 1)
      asm volatile("s_waitcnt vmcnt(8)" ::: "memory");   // cur buffer complete
    } else {
      asm volatile("s_waitcnt vmcnt(0)" ::: "memory");
    }
    __builtin_amdgcn_s_barrier();
    __builtin_amdgcn_sched_barrier(0);
    const u16* Kb = &KF[cur][0];
    const u16* Vb = &VF[cur][0];
    // ---- QK^T: 16 MFMAs (16x16x32), split into 2 independent chains ----
    __builtin_amdgcn_s_setprio(1);
    f32x4 sa = (f32x4){0.f, 0.f, 0.f, 0.f};
    f32x4 sb = (f32x4){0.f, 0.f, 0.f, 0.f};
    #pragma unroll
    for (int ck = 0; ck < 8; ck++) {
      int sl0 = ((lr * 64 + ck * 4 + lg) ^ (lr & 7)) * 8;
      int sl1 = ((lr * 64 + (ck + 8) * 4 + lg) ^ (lr & 7)) * 8;
      short8 k0 = *(const short8*)&Kb[sl0];
      short8 k1 = *(const short8*)&Kb[sl1];
      sa = __builtin_amdgcn_mfma_f32_16x16x32_bf16(k0, qf[ck], sa, 0, 0, 0);
      sb = __builtin_amdgcn_mfma_f32_16x16x32_bf16(k1, qf[ck + 8], sb, 0, 0, 0);
    }
    __builtin_amdgcn_s_setprio(0);
    f32x4 s0 = sa + sb;
    // lane: S[key=lg*4+r][q=lr] in s0[r]
    float pmax = -1e30f;
    #pragma unroll
    for (int r = 0; r < 4; r++) {
      s0[r] *= 0.125f;
      if (lg * 4 + r < nv) pmax = fmaxf(pmax, s0[r]);
    }
    pmax = fmaxf(pmax, __shfl_xor(pmax, 16));
    pmax = fmaxf(pmax, __shfl_xor(pmax, 32));          // row max (per q=lr)
    if (__any(pmax - m > 8.f)) {                       // deferred rescale (rare)
      float mnew = fmaxf(m, pmax);
      float rs = __expf(m - mnew);
      float rsr[4];
      #pragma unroll
      for (int r = 0; r < 4; r++) rsr[r] = __shfl(rs, lg * 4 + r);
      #pragma unroll
      for (int j = 0; j < 32; j++)
        #pragma unroll
        for (int r = 0; r < 4; r++) acc[j][r] *= rsr[r];
      l *= rs;
      m = mnew;
    }
    // ---- P = exp(S - m), in-register A-frag for 16x16x16 ----
    float p0 = (lg * 4 + 0 < nv) ? __expf(s0[0] - m) : 0.f;
    float p1 = (lg * 4 + 1 < nv) ? __expf(s0[1] - m) : 0.f;
    float p2 = (lg * 4 + 2 < nv) ? __expf(s0[2] - m) : 0.f;
    float p3 = (lg * 4 + 3 < nv) ? __expf(s0[3] - m) : 0.f;
    float psum = p0 + p1 + p2 + p3;
    psum += __shfl_xor(psum, 16);
    psum += __shfl_xor(psum, 32);
    l += psum;
    u32 pw[2] = { pack2(p0, p1), pack2(p2, p3) };
    s16x4 pf = *(const s16x4*)pw;
    // ---- PV: 32 MFMAs (16x16x16), V-frag b64 from swizzled LDS ----
    __builtin_amdgcn_s_setprio(1);
    #pragma unroll
    for (int ct = 0; ct < 32; ct++) {
      s16x4 vf = *(const s16x4*)&Vb[ct * 256 + vrd];
      acc[ct] = mfma16(pf, vf, acc[ct]);
    }
    __builtin_amdgcn_s_setprio(0);
    __builtin_amdgcn_s_barrier();            // all waves done reading cur
  }
  // cover MFMA-write -> VALU-read hazard before epilogue (inline-asm path)
  asm volatile("s_nop 7\n\ts_nop 7" :::);
  // ---- epilogue: normalize by l, store ----
  float linv = 1.f / l;
  float li[4];
  #pragma unroll
  for (int r = 0; r < 4; r++) li[r] = __shfl(linv, lg * 4 + r);
  #pragma unroll
  for (int ct = 0; ct < 32; ct++) {
    #pragma unroll
    for (int r = 0; r < 4; r++) {
      int q = q0 + lg * 4 + r;
      if (q < NN)
        xo[((size_t)(b * NN + q) * FF + f) * CC + ct * 16 + lr] = f2bf(acc[ct][r] * li[r]);
    }
  }
  #undef STAGE_KV
}

// ---------- softmax over F=5, in place on attn2 ----------
__global__ __launch_bounds__(256) void softmax_f5(float* __restrict__ a) {
  int t = blockIdx.x * 256 + threadIdx.x;
  if (t >= NB * 8 * NN) return;
  float* p = a + (size_t)t * FF;
  float l0 = p[0], l1 = p[1], l2 = p[2], l3 = p[3], l4 = p[4];
  float m = fmaxf(fmaxf(fmaxf(l0, l1), fmaxf(l2, l3)), l4);
  float e0 = __expf(l0 - m), e1 = __expf(l1 - m), e2 = __expf(l2 - m),
        e3 = __expf(l3 - m), e4 = __expf(l4 - m);
  float inv = 1.f / (e0 + e1 + e2 + e3 + e4);
  p[0] = e0 * inv; p[1] = e1 * inv; p[2] = e2 * inv; p[3] = e3 * inv; p[4] = e4 * inv;
}

// ---------- sentinel ----------
__global__ void sentinel_fill(float* o) { o[threadIdx.x] = 777.0f; }

// ---------- launcher ----------
extern "C" void kernel_launch(void* const* d_in, const int* in_sizes, int n_in,
                              void* d_out, int out_size, void* d_ws, size_t ws_size,
                              hipStream_t stream) {
  const float* x     = (const float*)d_in[0];
  const float* Wqkv  = (const float*)d_in[1];
  const float* Wq2   = (const float*)d_in[2];
  const float* Wkv2  = (const float*)d_in[3];
  const float* Wproj = (const float*)d_in[4];
  const float* bproj = (const float*)d_in[5];
  float* out   = (float*)d_out;
  float* attn2 = out + (size_t)PP * NB * FF * CC;

  char* ws = (char*)d_ws;
  const size_t SZ  = (size_t)18400 * CC * 2;            // 18.8 MB
  const size_t VT2 = (size_t)20 * NCHUNK * 8192 * 2;    // 19.0 MB (chunk-blocked V)
  const size_t XO  = (size_t)92000 * CC * 2;            // 94.2 MB
  const size_t WT  = (size_t)(1536 + 512 + 1024 + 512) * 512 * 2;  // 3.67 MB
  const size_t NEED = 2 * SZ + VT2 + XO + WT;           // ~154.6 MB
  if (ws_size < NEED) {
    sentinel_fill<<<1, 256, 0, stream>>>(out);
    return;
  }
  u16* q    = (u16*)(ws);
  u16* k    = (u16*)(ws + SZ);
  u16* vt   = (u16*)(ws + 2 * SZ);
  u16* xo   = (u16*)(ws + 2 * SZ + VT2);
  u16* wt_qkv  = (u16*)(ws + 2 * SZ + VT2 + XO);
  u16* wt_q2   = wt_qkv + (size_t)1536 * 512;
  u16* wt_kv2  = wt_q2  + (size_t)512 * 512;
  u16* wt_proj = wt_kv2 + (size_t)1024 * 512;
  u16* q2   = (u16*)(ws);            // alias q (dead after stage1)
  u16* outp = (u16*)(ws + SZ);       // alias k (dead after stage1)

  // 0) weight transpose + bf16 conversion
  wtrans<<<dim3(48, 16), 256, 0, stream>>>(Wqkv,  wt_qkv,  1536);
  wtrans<<<dim3(16, 16), 256, 0, stream>>>(Wq2,   wt_q2,   512);
  wtrans<<<dim3(32, 16), 256, 0, stream>>>(Wkv2,  wt_kv2,  1024);
  wtrans<<<dim3(16, 16), 256, 0, stream>>>(Wproj, wt_proj, 512);

  // 1) QKV projection (MFMA; v written chunk-blocked-16 transposed)
  {
    AProvX ap{x}; CSinkQKV cs{q, k, vt};
    mgemm128<<<dim3(12, 144), 256, 0, stream>>>(ap, wt_qkv, cs, 18400);
  }
  // 2) stage-1 space attention (R11 structure, dense-chunk DMA, pair-affinity) -> xo
  stage1_mfma6<<<1440, 256, 0, stream>>>(q, k, vt, xo);
  // 3) q2 = diag(xo) @ W_q2 * scale   (overwrites q region)
  {
    AProvDiag ap{xo}; CSinkQ2 cs{q2};
    mgemm128<<<dim3(4, 144), 256, 0, stream>>>(ap, wt_q2, cs, 18400);
  }
  // 4) fused k2-GEMM + q2 dot -> raw logits into attn2 slice of d_out
  mgemm_logits<<<dim3(4, 719), 256, 0, stream>>>(xo, q2, wt_kv2, attn2);
  // 5) softmax over F in place
  softmax_f5<<<(NB * 8 * NN + 255) / 256, 256, 0, stream>>>(attn2);
  // 6) fused mix + W_v2 -> out_pre (overwrites k region); BN=64, head = blockIdx.x
  {
    AProvMix ap{xo, attn2}; CSinkBF512 cs{outp};
    mgemm64<<<dim3(8, 144), 256, 0, stream>>>(ap, wt_kv2 + (size_t)512 * 512, cs, 18400);
  }
  // 7) final projection + bias + permute to (P, B*F, C)
  {
    AProvBF ap{outp, 18400}; CSinkProj cs{out, bproj};
    mgemm128<<<dim3(4, 144), 256, 0, stream>>>(ap, wt_proj, cs, 18400);
  }
}

// Round 16
// 812.629 us; speedup vs baseline: 2.2907x; 1.0016x over previous
//
#include <hip/hip_runtime.h>
#include <hip/hip_bf16.h>
#include <stdint.h>

typedef unsigned short u16;
typedef unsigned int   u32;
typedef __attribute__((ext_vector_type(8))) short short8;
typedef __attribute__((ext_vector_type(4))) short s16x4;
typedef __attribute__((ext_vector_type(4))) float f32x4;

// ---------- 16x16x16 bf16 MFMA: builtin if available (device pass), else inline asm ----------
__device__ __forceinline__ f32x4 mfma16(s16x4 a, s16x4 b, f32x4 c) {
#if defined(__HIP_DEVICE_COMPILE__)
#if __has_builtin(__builtin_amdgcn_mfma_f32_16x16x16bf16_1k)
  return __builtin_amdgcn_mfma_f32_16x16x16bf16_1k(a, b, c, 0, 0, 0);
#else
  asm volatile("s_nop 1\n\tv_mfma_f32_16x16x16_bf16 %0, %1, %2, %0"
               : "+v"(c) : "v"(a), "v"(b));
  return c;
#endif
#else
  return c;  // host pass: never executed
#endif
}

// ---------- bf16 helpers (storage-only bf16, f32 math) ----------
__device__ __forceinline__ float bf2f(u16 a) {
  union { u32 i; float f; } t; t.i = ((u32)a) << 16; return t.f;
}
__device__ __forceinline__ u16 f2bf(float f) {
  union { u32 i; float f; } t; t.f = f;
  u32 r = t.i + 0x7fffu + ((t.i >> 16) & 1u);   // round-nearest-even
  return (u16)(r >> 16);
}
__device__ __forceinline__ u32 pack2(float a, float b) {
  return (u32)f2bf(a) | ((u32)f2bf(b) << 16);
}
__device__ __forceinline__ void unpack8(uint4 u, float* o) {
  union { u32 i; float f; } t;
  t.i = u.x << 16;         o[0] = t.f;
  t.i = u.x & 0xffff0000u; o[1] = t.f;
  t.i = u.y << 16;         o[2] = t.f;
  t.i = u.y & 0xffff0000u; o[3] = t.f;
  t.i = u.z << 16;         o[4] = t.f;
  t.i = u.z & 0xffff0000u; o[5] = t.f;
  t.i = u.w << 16;         o[6] = t.f;
  t.i = u.w & 0xffff0000u; o[7] = t.f;
}

// async global->LDS 16B per lane; LDS dest is wave-uniform base + lane*16
__device__ __forceinline__ void gload16(const u16* g, u16* l) {
  __builtin_amdgcn_global_load_lds(
      (const __attribute__((address_space(1))) unsigned int*)g,
      (__attribute__((address_space(3))) unsigned int*)l, 16, 0, 0);
}

#define NB 4
#define NN 4600
#define FF 5
#define PP 920
#define CC 512
#define NCHUNK 58   // ceil(920/16); chunk 57 has 8 valid keys

// ---------- weight transpose + bf16: W[512][Nc] f32 -> Wt[Nc][512] bf16 ----------
__global__ __launch_bounds__(256) void wtrans(const float* __restrict__ W,
                                              u16* __restrict__ Wt, int Nc) {
  __shared__ float tile[32][33];
  const int nb = blockIdx.x * 32, kb = blockIdx.y * 32;
  const int tx = threadIdx.x & 31, ty = threadIdx.x >> 5;
  #pragma unroll
  for (int i = 0; i < 4; i++)
    tile[ty + i * 8][tx] = W[(size_t)(kb + ty + i * 8) * Nc + nb + tx];
  __syncthreads();
  #pragma unroll
  for (int i = 0; i < 4; i++)
    Wt[(size_t)(nb + ty + i * 8) * 512 + kb + tx] = f2bf(tile[tx][ty + i * 8]);
}

// ---------- A providers ----------
struct AProvX {        // x[n,b,c] f32, row r=(b,n); VALU-staged
  static constexpr bool RAW = false;
  const float* x;
  __device__ __forceinline__ void ldrow16(int r, int k0, float* o) const {
    if (r >= 18400) { for (int j = 0; j < 16; j++) o[j] = 0.f; return; }
    int b = r / NN, n = r - b * NN;
    const float* s = x + ((size_t)n * NB + b) * CC + k0;
    #pragma unroll
    for (int j = 0; j < 4; j++) {
      float4 v = *(const float4*)(s + j * 4);
      o[j * 4] = v.x; o[j * 4 + 1] = v.y; o[j * 4 + 2] = v.z; o[j * 4 + 3] = v.w;
    }
  }
  __device__ __forceinline__ const u16* gptr(int, int) const { return nullptr; }
};
struct AProvBF {       // contiguous bf16 rows, stride 512; DMA-staged
  static constexpr bool RAW = true;
  const u16* a; int M;
  __device__ __forceinline__ void ldrow16(int, int, float*) const {}
  __device__ __forceinline__ const u16* gptr(int r, int k) const {
    int rc = r < M ? r : M - 1;
    return a + (size_t)rc * CC + k;
  }
};
struct AProvDiag {     // x_diag: row (b,n) -> xo[b,n, n/P, c]; DMA-staged
  static constexpr bool RAW = true;
  const u16* xo;
  __device__ __forceinline__ void ldrow16(int, int, float*) const {}
  __device__ __forceinline__ const u16* gptr(int r, int k) const {
    int rc = r < 18400 ? r : 18399;
    int b = rc / NN, n = rc - b * NN;
    int f = n / PP;
    return xo + (((size_t)b * NN + n) * FF + f) * CC + k;
  }
};
struct AProvMix {      // mixed_h[r][k] = sum_f attn2[b,h,s,f] * xo[r,f,k]; VALU-staged
  static constexpr bool RAW = false;
  const u16* xo; const float* attn2;
  __device__ __forceinline__ void ldrow16(int r, int k0, float* o) const {
    if (r >= 18400) { for (int j = 0; j < 16; j++) o[j] = 0.f; return; }
    int h = blockIdx.x;
    int b = r / NN, s = r - b * NN;
    const float* aw = attn2 + (((size_t)b * 8 + h) * NN + s) * FF;
    float w[5];
    #pragma unroll
    for (int f = 0; f < FF; f++) w[f] = aw[f];
    #pragma unroll
    for (int j = 0; j < 16; j++) o[j] = 0.f;
    const u16* base = xo + (size_t)r * FF * CC + k0;
    #pragma unroll
    for (int f = 0; f < FF; f++) {
      float t[16];
      const u16* s2 = base + (size_t)f * CC;
      unpack8(*(const uint4*)s2, t);
      unpack8(*(const uint4*)(s2 + 8), t + 8);
      #pragma unroll
      for (int j = 0; j < 16; j++) o[j] = fmaf(w[f], t[j], o[j]);
    }
  }
  __device__ __forceinline__ const u16* gptr(int, int) const { return nullptr; }
};

// ---------- C sinks ----------
struct CSinkQKV {      // q,k row-major; v chunk-blocked(16) transposed
  u16 *q, *k, *vt;
  __device__ __forceinline__ void st(int r, int c, float val) const {
    u16 hv = f2bf(val);
    if (c < 512)        q[(size_t)r * CC + c] = hv;
    else if (c < 1024)  k[(size_t)r * CC + (c - 512)] = hv;
    else {
      int b = r / NN, n = r - b * NN;
      int f = n / PP, p = n - f * PP;
      size_t idx = (((size_t)(b * FF + f) * NCHUNK + (p >> 4)) * 512 + (c - 1024)) * 16 + (p & 15);
      vt[idx] = hv;
    }
  }
};
struct CSinkQ2 {
  u16* o;
  __device__ __forceinline__ void st(int r, int c, float v) const {
    o[(size_t)r * CC + c] = f2bf(v * 0.125f);
  }
};
struct CSinkBF512 {
  u16* o;
  __device__ __forceinline__ void st(int r, int c, float v) const {
    o[(size_t)r * CC + c] = f2bf(v);
  }
};
struct CSinkProj {
  float* out; const float* bias;
  __device__ __forceinline__ void st(int r, int c, float v) const {
    int b = r / NN, rem = r - b * NN;
    int f = rem / PP, p = rem - f * PP;
    out[((size_t)p * (NB * FF) + b * FF + f) * CC + c] = v + bias[c];
  }
};

// ---------- MFMA GEMM, tile 128x128, single-buffer m97-style DMA staging ----------
template<class AP, class CS>
__global__ __launch_bounds__(256) void mgemm128(AP ap, const u16* __restrict__ Bt,
                                                CS cs, int M) {
  __shared__ __align__(16) u16 Al[128 * 32];   // linear [row][32]
  __shared__ __align__(16) u16 Bl[128 * 32];   // linear [col][32]
  const int tid = threadIdx.x;
  const int wid = tid >> 6, lane = tid & 63;
  const int lr = lane & 15, lg = lane >> 4;
  const int wr = wid >> 1, wc = wid & 1;
  const int row0 = blockIdx.y * 128, col0 = blockIdx.x * 128;
  const int srow = tid >> 1, skh = tid & 1;    // VALU staging assignment
  f32x4 acc[4][4];
  #pragma unroll
  for (int i = 0; i < 4; i++)
    #pragma unroll
    for (int j = 0; j < 4; j++) acc[i][j] = (f32x4){0.f, 0.f, 0.f, 0.f};

  for (int k0 = 0; k0 < 512; k0 += 32) {
    __syncthreads();               // prior tile's reads complete
    if constexpr (AP::RAW) {       // A tile: 8 x 1KB DMA (2 per wave)
      #pragma unroll
      for (int c = 0; c < 2; c++) {
        int inst = wid * 2 + c;
        int r = row0 + inst * 16 + (lane >> 2);
        gload16(ap.gptr(r, k0 + (lane & 3) * 8), &Al[inst * 512]);
      }
    } else {                       // A tile: VALU-staged (compute-generated)
      float tmp[16];
      ap.ldrow16(row0 + srow, k0 + skh * 16, tmp);
      u16 tb[16];
      #pragma unroll
      for (int j = 0; j < 16; j++) tb[j] = f2bf(tmp[j]);
      *(uint4*)&Al[srow * 32 + skh * 16]     = *(const uint4*)&tb[0];
      *(uint4*)&Al[srow * 32 + skh * 16 + 8] = *(const uint4*)&tb[8];
    }
    #pragma unroll
    for (int c = 0; c < 2; c++) {  // B tile: 8 x 1KB DMA (2 per wave)
      int inst = wid * 2 + c;
      int col = col0 + inst * 16 + (lane >> 2);
      gload16(Bt + (size_t)col * 512 + k0 + (lane & 3) * 8, &Bl[inst * 512]);
    }
    __syncthreads();               // full drain (vmcnt0+lgkmcnt0) + barrier
    short8 afr[4], bfr[4];
    #pragma unroll
    for (int mt = 0; mt < 4; mt++)
      afr[mt] = *(const short8*)&Al[(wr * 64 + mt * 16 + lr) * 32 + lg * 8];
    #pragma unroll
    for (int ct = 0; ct < 4; ct++)
      bfr[ct] = *(const short8*)&Bl[(wc * 64 + ct * 16 + lr) * 32 + lg * 8];
    #pragma unroll
    for (int mt = 0; mt < 4; mt++)
      #pragma unroll
      for (int ct = 0; ct < 4; ct++)
        acc[mt][ct] = __builtin_amdgcn_mfma_f32_16x16x32_bf16(afr[mt], bfr[ct], acc[mt][ct], 0, 0, 0);
  }
  #pragma unroll
  for (int mt = 0; mt < 4; mt++)
    #pragma unroll
    for (int ct = 0; ct < 4; ct++)
      #pragma unroll
      for (int r = 0; r < 4; r++) {
        int rr = row0 + wr * 64 + mt * 16 + lg * 4 + r;
        if (rr < M)
          cs.st(rr, col0 + wc * 64 + ct * 16 + lr, acc[mt][ct][r]);
      }
}

// ---------- MFMA GEMM, tile 128x64 (Mix: VALU-A + DMA-B), single-buffer ----------
template<class AP, class CS>
__global__ __launch_bounds__(256) void mgemm64(AP ap, const u16* __restrict__ Bt,
                                               CS cs, int M) {
  __shared__ __align__(16) u16 Al[128 * 32];
  __shared__ __align__(16) u16 Bl[64 * 32];
  const int tid = threadIdx.x;
  const int wid = tid >> 6, lane = tid & 63;
  const int lr = lane & 15, lg = lane >> 4;
  const int row0 = blockIdx.y * 128, col0 = blockIdx.x * 64;
  const int srow = tid >> 1, skh = tid & 1;
  f32x4 acc[2][4];
  #pragma unroll
  for (int i = 0; i < 2; i++)
    #pragma unroll
    for (int j = 0; j < 4; j++) acc[i][j] = (f32x4){0.f, 0.f, 0.f, 0.f};

  for (int k0 = 0; k0 < 512; k0 += 32) {
    __syncthreads();
    {
      float tmp[16];
      ap.ldrow16(row0 + srow, k0 + skh * 16, tmp);
      u16 tb[16];
      #pragma unroll
      for (int j = 0; j < 16; j++) tb[j] = f2bf(tmp[j]);
      *(uint4*)&Al[srow * 32 + skh * 16]     = *(const uint4*)&tb[0];
      *(uint4*)&Al[srow * 32 + skh * 16 + 8] = *(const uint4*)&tb[8];
    }
    {
      int col = col0 + wid * 16 + (lane >> 2);
      gload16(Bt + (size_t)col * 512 + k0 + (lane & 3) * 8, &Bl[wid * 512]);
    }
    __syncthreads();
    short8 afr[2], bfr[4];
    #pragma unroll
    for (int mt = 0; mt < 2; mt++)
      afr[mt] = *(const short8*)&Al[(wid * 32 + mt * 16 + lr) * 32 + lg * 8];
    #pragma unroll
    for (int ct = 0; ct < 4; ct++)
      bfr[ct] = *(const short8*)&Bl[(ct * 16 + lr) * 32 + lg * 8];
    #pragma unroll
    for (int mt = 0; mt < 2; mt++)
      #pragma unroll
      for (int ct = 0; ct < 4; ct++)
        acc[mt][ct] = __builtin_amdgcn_mfma_f32_16x16x32_bf16(afr[mt], bfr[ct], acc[mt][ct], 0, 0, 0);
  }
  #pragma unroll
  for (int mt = 0; mt < 2; mt++)
    #pragma unroll
    for (int ct = 0; ct < 4; ct++)
      #pragma unroll
      for (int r = 0; r < 4; r++) {
        int rr = row0 + wid * 32 + mt * 16 + lg * 4 + r;
        if (rr < M)
          cs.st(rr, col0 + ct * 16 + lr, acc[mt][ct][r]);
      }
}

// ---------- logits: k2 = xo @ Wk2 (single-buffer DMA), epilogue dot with q2 ----------
__global__ __launch_bounds__(256) void mgemm_logits(const u16* __restrict__ xo,
                                                    const u16* __restrict__ q2,
                                                    const u16* __restrict__ Wk2t,
                                                    float* __restrict__ attn2) {
  __shared__ __align__(16) u16 Al[128 * 32];
  __shared__ __align__(16) u16 Bl[128 * 32];
  const int tid = threadIdx.x;
  const int wid = tid >> 6, lane = tid & 63;
  const int lr = lane & 15, lg = lane >> 4;
  const int wr = wid >> 1, wc = wid & 1;
  const int row0 = blockIdx.y * 128, col0 = blockIdx.x * 128;
  f32x4 acc[4][4];
  #pragma unroll
  for (int i = 0; i < 4; i++)
    #pragma unroll
    for (int j = 0; j < 4; j++) acc[i][j] = (f32x4){0.f, 0.f, 0.f, 0.f};

  for (int k0 = 0; k0 < 512; k0 += 32) {
    __syncthreads();
    #pragma unroll
    for (int c = 0; c < 2; c++) {
      int inst = wid * 2 + c;
      int r = row0 + inst * 16 + (lane >> 2);
      int rc = r < 92000 ? r : 91999;
      gload16(xo + (size_t)rc * CC + k0 + (lane & 3) * 8, &Al[inst * 512]);
    }
    #pragma unroll
    for (int c = 0; c < 2; c++) {
      int inst = wid * 2 + c;
      int col = col0 + inst * 16 + (lane >> 2);
      gload16(Wk2t + (size_t)col * 512 + k0 + (lane & 3) * 8, &Bl[inst * 512]);
    }
    __syncthreads();
    short8 afr[4], bfr[4];
    #pragma unroll
    for (int mt = 0; mt < 4; mt++)
      afr[mt] = *(const short8*)&Al[(wr * 64 + mt * 16 + lr) * 32 + lg * 8];
    #pragma unroll
    for (int ct = 0; ct < 4; ct++)
      bfr[ct] = *(const short8*)&Bl[(wc * 64 + ct * 16 + lr) * 32 + lg * 8];
    #pragma unroll
    for (int mt = 0; mt < 4; mt++)
      #pragma unroll
      for (int ct = 0; ct < 4; ct++)
        acc[mt][ct] = __builtin_amdgcn_mfma_f32_16x16x32_bf16(afr[mt], bfr[ct], acc[mt][ct], 0, 0, 0);
  }
  const int head = blockIdx.x * 2 + wc;
  #pragma unroll
  for (int mt = 0; mt < 4; mt++) {
    float part[4] = {0.f, 0.f, 0.f, 0.f};
    #pragma unroll
    for (int r = 0; r < 4; r++) {
      int rr = row0 + wr * 64 + mt * 16 + lg * 4 + r;
      int rc = rr < 92000 ? rr : 91999;
      const u16* qrow = q2 + (size_t)(rc / 5) * CC + head * 64 + lr;
      #pragma unroll
      for (int ct = 0; ct < 4; ct++)
        part[r] = fmaf(acc[mt][ct][r], bf2f(qrow[ct * 16]), part[r]);
    }
    #pragma unroll
    for (int r = 0; r < 4; r++) {
      float v = part[r];
      v += __shfl_xor(v, 1);
      v += __shfl_xor(v, 2);
      v += __shfl_xor(v, 4);
      v += __shfl_xor(v, 8);
      int rr = row0 + wr * 64 + mt * 16 + lg * 4 + r;
      if (lr == 0 && rr < 92000) {
        int b = rr / (NN * FF), rem = rr - b * (NN * FF);
        int s = rem / FF, f = rem - s * FF;
        attn2[(((size_t)b * 8 + head) * NN + s) * FF + f] = v;
      }
    }
  }
}

// ---------- stage 1 (R14 verbatim: 16-key chunks, dbuf DMA K+V, setprio) ----------
__global__ __launch_bounds__(256, 2) void stage1_mfma6(const u16* __restrict__ qg,
                                                       const u16* __restrict__ kg,
                                                       const u16* __restrict__ vt,
                                                       u16* __restrict__ xo) {
  __shared__ __align__(16) u16 KF[2][16 * 512];   // 2 x 16 KB
  __shared__ __align__(16) u16 VF[2][512 * 16];   // 2 x 16 KB
  const int tid = threadIdx.x;
  const int wid = tid >> 6, lane = tid & 63;
  const int lr = lane & 15, lg = lane >> 4;
  const int wgid = blockIdx.x;
  const int g = (wgid & 7) * 180 + (wgid >> 3);
  const int pair = g / 72, qt = g - pair * 72;
  const int b = pair / 5, f = pair - b * 5;
  const int q0 = qt * 64 + wid * 16;

  const u16* kbase = kg + ((size_t)b * NN + f * PP) * CC;
  const u16* vpair = vt + (size_t)pair * NCHUNK * 8192;

  short8 qf[16];
  {
    int qrow = q0 + lr; if (qrow > NN - 1) qrow = NN - 1;
    const u16* qb = qg + ((size_t)b * NN + qrow) * CC + lg * 8;
    #pragma unroll
    for (int ck = 0; ck < 16; ck++) qf[ck] = *(const short8*)(qb + ck * 32);
  }
  asm volatile("s_waitcnt vmcnt(0)" ::: "memory");

  #define STAGE_KV(buf, kk0v, ckv)                                             \
    {                                                                          \
      const int kk0_ = (kk0v);                                                 \
      const u16* vcb_ = vpair + (size_t)(ckv) * 8192;                          \
      _Pragma("unroll")                                                        \
      for (int c = 0; c < 4; c++) {                                            \
        int r = wid * 4 + c;                                                   \
        int key = kk0_ + r; if (key > PP - 1) key = PP - 1;                    \
        const u16* src = kbase + (size_t)key * CC + ((lane ^ (r & 7)) * 8);    \
        gload16(src, &KF[buf][r * 512]);                                       \
      }                                                                        \
      _Pragma("unroll")                                                        \
      for (int c = 0; c < 4; c++) {                                            \
        int j = wid * 4 + c;                                                   \
        int ulin = j * 64 + lane;                                              \
        int uc = ulin ^ ((ulin >> 3) & 3);                                     \
        gload16(vcb_ + uc * 8, &VF[buf][j * 512]);                             \
      }                                                                        \
    }

  STAGE_KV(0, 0, 0)

  f32x4 acc[32];
  #pragma unroll
  for (int j = 0; j < 32; j++) acc[j] = (f32x4){0.f, 0.f, 0.f, 0.f};
  float m = 0.f, l = 0.f;

  const int vrd = (((2 * lr + (lg >> 1)) ^ (lr >> 2)) * 8) + (lg & 1) * 4;

  for (int ch = 0; ch < NCHUNK; ch++) {
    const int kk0 = ch * 16;
    const int nv = (ch == NCHUNK - 1) ? 8 : 16;
    const int cur = ch & 1, nxt = cur ^ 1;
    if (ch < NCHUNK - 1) {
      STAGE_KV(nxt, kk0 + 16, ch + 1)
      asm volatile("s_waitcnt vmcnt(8)" ::: "memory");
    } else {
      asm volatile("s_waitcnt vmcnt(0)" ::: "memory");
    }
    __builtin_amdgcn_s_barrier();
    __builtin_amdgcn_sched_barrier(0);
    const u16* Kb = &KF[cur][0];
    const u16* Vb = &VF[cur][0];
    __builtin_amdgcn_s_setprio(1);
    f32x4 sa = (f32x4){0.f, 0.f, 0.f, 0.f};
    f32x4 sb = (f32x4){0.f, 0.f, 0.f, 0.f};
    #pragma unroll
    for (int ck = 0; ck < 8; ck++) {
      int sl0 = ((lr * 64 + ck * 4 + lg) ^ (lr & 7)) * 8;
      int sl1 = ((lr * 64 + (ck + 8) * 4 + lg) ^ (lr & 7)) * 8;
      short8 k0 = *(const short8*)&Kb[sl0];
      short8 k1 = *(const short8*)&Kb[sl1];
      sa = __builtin_amdgcn_mfma_f32_16x16x32_bf16(k0, qf[ck], sa, 0, 0, 0);
      sb = __builtin_amdgcn_mfma_f32_16x16x32_bf16(k1, qf[ck + 8], sb, 0, 0, 0);
    }
    __builtin_amdgcn_s_setprio(0);
    f32x4 s0 = sa + sb;
    float pmax = -1e30f;
    #pragma unroll
    for (int r = 0; r < 4; r++) {
      s0[r] *= 0.125f;
      if (lg * 4 + r < nv) pmax = fmaxf(pmax, s0[r]);
    }
    pmax = fmaxf(pmax, __shfl_xor(pmax, 16));
    pmax = fmaxf(pmax, __shfl_xor(pmax, 32));
    if (__any(pmax - m > 8.f)) {
      float mnew = fmaxf(m, pmax);
      float rs = __expf(m - mnew);
      float rsr[4];
      #pragma unroll
      for (int r = 0; r < 4; r++) rsr[r] = __shfl(rs, lg * 4 + r);
      #pragma unroll
      for (int j = 0; j < 32; j++)
        #pragma unroll
        for (int r = 0; r < 4; r++) acc[j][r] *= rsr[r];
      l *= rs;
      m = mnew;
    }
    float p0 = (lg * 4 + 0 < nv) ? __expf(s0[0] - m) : 0.f;
    float p1 = (lg * 4 + 1 < nv) ? __expf(s0[1] - m) : 0.f;
    float p2 = (lg * 4 + 2 < nv) ? __expf(s0[2] - m) : 0.f;
    float p3 = (lg * 4 + 3 < nv) ? __expf(s0[3] - m) : 0.f;
    float psum = p0 + p1 + p2 + p3;
    psum += __shfl_xor(psum, 16);
    psum += __shfl_xor(psum, 32);
    l += psum;
    u32 pw[2] = { pack2(p0, p1), pack2(p2, p3) };
    s16x4 pf = *(const s16x4*)pw;
    __builtin_amdgcn_s_setprio(1);
    #pragma unroll
    for (int ct = 0; ct < 32; ct++) {
      s16x4 vf = *(const s16x4*)&Vb[ct * 256 + vrd];
      acc[ct] = mfma16(pf, vf, acc[ct]);
    }
    __builtin_amdgcn_s_setprio(0);
    __builtin_amdgcn_s_barrier();
  }
  asm volatile("s_nop 7\n\ts_nop 7" :::);
  float linv = 1.f / l;
  float li[4];
  #pragma unroll
  for (int r = 0; r < 4; r++) li[r] = __shfl(linv, lg * 4 + r);
  #pragma unroll
  for (int ct = 0; ct < 32; ct++) {
    #pragma unroll
    for (int r = 0; r < 4; r++) {
      int q = q0 + lg * 4 + r;
      if (q < NN)
        xo[((size_t)(b * NN + q) * FF + f) * CC + ct * 16 + lr] = f2bf(acc[ct][r] * li[r]);
    }
  }
  #undef STAGE_KV
}

// ---------- softmax over F=5, in place on attn2 ----------
__global__ __launch_bounds__(256) void softmax_f5(float* __restrict__ a) {
  int t = blockIdx.x * 256 + threadIdx.x;
  if (t >= NB * 8 * NN) return;
  float* p = a + (size_t)t * FF;
  float l0 = p[0], l1 = p[1], l2 = p[2], l3 = p[3], l4 = p[4];
  float m = fmaxf(fmaxf(fmaxf(l0, l1), fmaxf(l2, l3)), l4);
  float e0 = __expf(l0 - m), e1 = __expf(l1 - m), e2 = __expf(l2 - m),
        e3 = __expf(l3 - m), e4 = __expf(l4 - m);
  float inv = 1.f / (e0 + e1 + e2 + e3 + e4);
  p[0] = e0 * inv; p[1] = e1 * inv; p[2] = e2 * inv; p[3] = e3 * inv; p[4] = e4 * inv;
}

// ---------- sentinel ----------
__global__ void sentinel_fill(float* o) { o[threadIdx.x] = 777.0f; }

// ---------- launcher ----------
extern "C" void kernel_launch(void* const* d_in, const int* in_sizes, int n_in,
                              void* d_out, int out_size, void* d_ws, size_t ws_size,
                              hipStream_t stream) {
  const float* x     = (const float*)d_in[0];
  const float* Wqkv  = (const float*)d_in[1];
  const float* Wq2   = (const float*)d_in[2];
  const float* Wkv2  = (const float*)d_in[3];
  const float* Wproj = (const float*)d_in[4];
  const float* bproj = (const float*)d_in[5];
  float* out   = (float*)d_out;
  float* attn2 = out + (size_t)PP * NB * FF * CC;

  char* ws = (char*)d_ws;
  const size_t SZ  = (size_t)18400 * CC * 2;            // 18.8 MB
  const size_t VT2 = (size_t)20 * NCHUNK * 8192 * 2;    // 19.0 MB (chunk-blocked V)
  const size_t XO  = (size_t)92000 * CC * 2;            // 94.2 MB
  const size_t WT  = (size_t)(1536 + 512 + 1024 + 512) * 512 * 2;  // 3.67 MB
  const size_t NEED = 2 * SZ + VT2 + XO + WT;           // ~154.6 MB
  if (ws_size < NEED) {
    sentinel_fill<<<1, 256, 0, stream>>>(out);
    return;
  }
  u16* q    = (u16*)(ws);
  u16* k    = (u16*)(ws + SZ);
  u16* vt   = (u16*)(ws + 2 * SZ);
  u16* xo   = (u16*)(ws + 2 * SZ + VT2);
  u16* wt_qkv  = (u16*)(ws + 2 * SZ + VT2 + XO);
  u16* wt_q2   = wt_qkv + (size_t)1536 * 512;
  u16* wt_kv2  = wt_q2  + (size_t)512 * 512;
  u16* wt_proj = wt_kv2 + (size_t)1024 * 512;
  u16* q2   = (u16*)(ws);            // alias q (dead after stage1)
  u16* outp = (u16*)(ws + SZ);       // alias k (dead after stage1)

  // 0) weight transpose + bf16 conversion
  wtrans<<<dim3(48, 16), 256, 0, stream>>>(Wqkv,  wt_qkv,  1536);
  wtrans<<<dim3(16, 16), 256, 0, stream>>>(Wq2,   wt_q2,   512);
  wtrans<<<dim3(32, 16), 256, 0, stream>>>(Wkv2,  wt_kv2,  1024);
  wtrans<<<dim3(16, 16), 256, 0, stream>>>(Wproj, wt_proj, 512);

  // 1) QKV projection (VALU-A + DMA-B; v written chunk-blocked-16 transposed)
  {
    AProvX ap{x}; CSinkQKV cs{q, k, vt};
    mgemm128<<<dim3(12, 144), 256, 0, stream>>>(ap, wt_qkv, cs, 18400);
  }
  // 2) stage-1 space attention (R14 structure) -> xo
  stage1_mfma6<<<1440, 256, 0, stream>>>(q, k, vt, xo);
  // 3) q2 = diag(xo) @ W_q2 * scale (DMA-A + DMA-B, full drain)
  {
    AProvDiag ap{xo}; CSinkQ2 cs{q2};
    mgemm128<<<dim3(4, 144), 256, 0, stream>>>(ap, wt_q2, cs, 18400);
  }
  // 4) fused k2-GEMM + q2 dot -> raw logits (DMA, full drain)
  mgemm_logits<<<dim3(4, 719), 256, 0, stream>>>(xo, q2, wt_kv2, attn2);
  // 5) softmax over F in place
  softmax_f5<<<(NB * 8 * NN + 255) / 256, 256, 0, stream>>>(attn2);
  // 6) fused mix + W_v2 -> out_pre (VALU-A + DMA-B); head = blockIdx.x
  {
    AProvMix ap{xo, attn2}; CSinkBF512 cs{outp};
    mgemm64<<<dim3(8, 144), 256, 0, stream>>>(ap, wt_kv2 + (size_t)512 * 512, cs, 18400);
  }
  // 7) final projection + bias + permute (DMA, full drain)
  {
    AProvBF ap{outp, 18400}; CSinkProj cs{out, bproj};
    mgemm128<<<dim3(4, 144), 256, 0, stream>>>(ap, wt_proj, cs, 18400);
  }
}

// Round 17
// 667.835 us; speedup vs baseline: 2.7873x; 1.2168x over previous
//
#include <hip/hip_runtime.h>
#include <hip/hip_bf16.h>
#include <stdint.h>

typedef unsigned short u16;
typedef unsigned int   u32;
typedef __attribute__((ext_vector_type(8))) short short8;
typedef __attribute__((ext_vector_type(4))) short s16x4;
typedef __attribute__((ext_vector_type(4))) float f32x4;

// ---------- 16x16x16 bf16 MFMA: builtin if available (device pass), else inline asm ----------
__device__ __forceinline__ f32x4 mfma16(s16x4 a, s16x4 b, f32x4 c) {
#if defined(__HIP_DEVICE_COMPILE__)
#if __has_builtin(__builtin_amdgcn_mfma_f32_16x16x16bf16_1k)
  return __builtin_amdgcn_mfma_f32_16x16x16bf16_1k(a, b, c, 0, 0, 0);
#else
  asm volatile("s_nop 1\n\tv_mfma_f32_16x16x16_bf16 %0, %1, %2, %0"
               : "+v"(c) : "v"(a), "v"(b));
  return c;
#endif
#else
  return c;  // host pass: never executed
#endif
}

// ---------- bf16 helpers ----------
__device__ __forceinline__ float bf2f(u16 a) {
  union { u32 i; float f; } t; t.i = ((u32)a) << 16; return t.f;
}
__device__ __forceinline__ u16 f2bf(float f) {
  union { u32 i; float f; } t; t.f = f;
  u32 r = t.i + 0x7fffu + ((t.i >> 16) & 1u);
  return (u16)(r >> 16);
}
__device__ __forceinline__ u32 pack2(float a, float b) {
  return (u32)f2bf(a) | ((u32)f2bf(b) << 16);
}
__device__ __forceinline__ void unpack8(uint4 u, float* o) {
  union { u32 i; float f; } t;
  t.i = u.x << 16;         o[0] = t.f;
  t.i = u.x & 0xffff0000u; o[1] = t.f;
  t.i = u.y << 16;         o[2] = t.f;
  t.i = u.y & 0xffff0000u; o[3] = t.f;
  t.i = u.z << 16;         o[4] = t.f;
  t.i = u.z & 0xffff0000u; o[5] = t.f;
  t.i = u.w << 16;         o[6] = t.f;
  t.i = u.w & 0xffff0000u; o[7] = t.f;
}

__device__ __forceinline__ void gload16(const u16* g, u16* l) {
  __builtin_amdgcn_global_load_lds(
      (const __attribute__((address_space(1))) unsigned int*)g,
      (__attribute__((address_space(3))) unsigned int*)l, 16, 0, 0);
}

// bijective XCD-affinity remap (m204): consecutive remapped ids share a row-panel
__device__ __forceinline__ int xcd_remap(int wgid, int N) {
  int q = N >> 3, r = N & 7;
  int x = wgid & 7, i = wgid >> 3;
  int off = (x < r) ? x * (q + 1) : r * (q + 1) + (x - r) * q;
  return off + i;
}

#define NB 4
#define NN 4600
#define FF 5
#define PP 920
#define CC 512
#define NCHUNK 58

// ---------- weight transpose + bf16 ----------
__global__ __launch_bounds__(256) void wtrans(const float* __restrict__ W,
                                              u16* __restrict__ Wt, int Nc) {
  __shared__ float tile[32][33];
  const int nb = blockIdx.x * 32, kb = blockIdx.y * 32;
  const int tx = threadIdx.x & 31, ty = threadIdx.x >> 5;
  #pragma unroll
  for (int i = 0; i < 4; i++)
    tile[ty + i * 8][tx] = W[(size_t)(kb + ty + i * 8) * Nc + nb + tx];
  __syncthreads();
  #pragma unroll
  for (int i = 0; i < 4; i++)
    Wt[(size_t)(nb + ty + i * 8) * 512 + kb + tx] = f2bf(tile[tx][ty + i * 8]);
}

// ---------- x convert: f32 (S,B,C) -> bf16 rows r=(b,n) ----------
__global__ __launch_bounds__(256) void xcvt(const float* __restrict__ x,
                                            u16* __restrict__ xb) {
  int gid = blockIdx.x * 256 + threadIdx.x;
  int base = gid * 8;
  int r = base >> 9, c = base & 511;
  int b = r / NN, n = r - b * NN;
  const float* s = x + ((size_t)n * NB + b) * CC + c;
  float4 v0 = *(const float4*)s;
  float4 v1 = *(const float4*)(s + 4);
  uint4 o;
  o.x = pack2(v0.x, v0.y); o.y = pack2(v0.z, v0.w);
  o.z = pack2(v1.x, v1.y); o.w = pack2(v1.z, v1.w);
  *(uint4*)&xb[(size_t)r * CC + c] = o;
}

// ---------- A providers ----------
struct AProvBF {       // contiguous bf16 rows, stride 512; DMA-staged
  static constexpr bool RAW = true;
  const u16* a; int M;
  __device__ __forceinline__ void ldrow16(int, int, float*, int) const {}
  __device__ __forceinline__ const u16* gptr(int r, int k) const {
    int rc = r < M ? r : M - 1;
    return a + (size_t)rc * CC + k;
  }
};
struct AProvDiag {     // x_diag: row (b,n) -> xo[b,n, n/P, c]; DMA-staged
  static constexpr bool RAW = true;
  const u16* xo;
  __device__ __forceinline__ void ldrow16(int, int, float*, int) const {}
  __device__ __forceinline__ const u16* gptr(int r, int k) const {
    int rc = r < 18400 ? r : 18399;
    int b = rc / NN, n = rc - b * NN;
    int f = n / PP;
    return xo + (((size_t)b * NN + n) * FF + f) * CC + k;
  }
};
struct AProvMix {      // mixed_h[r][k]; h passed via aux; VALU-staged
  static constexpr bool RAW = false;
  const u16* xo; const float* attn2;
  __device__ __forceinline__ void ldrow16(int r, int k0, float* o, int h) const {
    if (r >= 18400) { for (int j = 0; j < 16; j++) o[j] = 0.f; return; }
    int b = r / NN, s = r - b * NN;
    const float* aw = attn2 + (((size_t)b * 8 + h) * NN + s) * FF;
    float w[5];
    #pragma unroll
    for (int f = 0; f < FF; f++) w[f] = aw[f];
    #pragma unroll
    for (int j = 0; j < 16; j++) o[j] = 0.f;
    const u16* base = xo + (size_t)r * FF * CC + k0;
    #pragma unroll
    for (int f = 0; f < FF; f++) {
      float t[16];
      const u16* s2 = base + (size_t)f * CC;
      unpack8(*(const uint4*)s2, t);
      unpack8(*(const uint4*)(s2 + 8), t + 8);
      #pragma unroll
      for (int j = 0; j < 16; j++) o[j] = fmaf(w[f], t[j], o[j]);
    }
  }
  __device__ __forceinline__ const u16* gptr(int, int) const { return nullptr; }
};

// ---------- C sinks ----------
struct CSinkQKV {
  u16 *q, *k, *vt;
  __device__ __forceinline__ void st(int r, int c, float val) const {
    u16 hv = f2bf(val);
    if (c < 512)        q[(size_t)r * CC + c] = hv;
    else if (c < 1024)  k[(size_t)r * CC + (c - 512)] = hv;
    else {
      int b = r / NN, n = r - b * NN;
      int f = n / PP, p = n - f * PP;
      size_t idx = (((size_t)(b * FF + f) * NCHUNK + (p >> 4)) * 512 + (c - 1024)) * 16 + (p & 15);
      vt[idx] = hv;
    }
  }
};
struct CSinkQ2 {
  u16* o;
  __device__ __forceinline__ void st(int r, int c, float v) const {
    o[(size_t)r * CC + c] = f2bf(v * 0.125f);
  }
};
struct CSinkBF512 {
  u16* o;
  __device__ __forceinline__ void st(int r, int c, float v) const {
    o[(size_t)r * CC + c] = f2bf(v);
  }
};
struct CSinkProj {
  float* out; const float* bias;
  __device__ __forceinline__ void st(int r, int c, float v) const {
    int b = r / NN, rem = r - b * NN;
    int f = rem / PP, p = rem - f * PP;
    out[((size_t)p * (NB * FF) + b * FF + f) * CC + c] = v + bias[c];
  }
};

// ---------- MFMA GEMM, tile 128x128, 1-D grid, XCD-affinity; single-buffer DMA ----------
template<class AP, class CS>
__global__ __launch_bounds__(256) void mgemm128(AP ap, const u16* __restrict__ Bt,
                                                CS cs, int M, int CB) {
  __shared__ __align__(16) u16 Al[128 * 32];
  __shared__ __align__(16) u16 Bl[128 * 32];
  const int tid = threadIdx.x;
  const int wid = tid >> 6, lane = tid & 63;
  const int lr = lane & 15, lg = lane >> 4;
  const int wr = wid >> 1, wc = wid & 1;
  const int g = xcd_remap(blockIdx.x, gridDim.x);
  const int row0 = (g / CB) * 128, col0 = (g % CB) * 128;
  const int srow = tid >> 1, skh = tid & 1;
  f32x4 acc[4][4];
  #pragma unroll
  for (int i = 0; i < 4; i++)
    #pragma unroll
    for (int j = 0; j < 4; j++) acc[i][j] = (f32x4){0.f, 0.f, 0.f, 0.f};

  for (int k0 = 0; k0 < 512; k0 += 32) {
    __syncthreads();
    if constexpr (AP::RAW) {
      #pragma unroll
      for (int c = 0; c < 2; c++) {
        int inst = wid * 2 + c;
        int r = row0 + inst * 16 + (lane >> 2);
        gload16(ap.gptr(r, k0 + (lane & 3) * 8), &Al[inst * 512]);
      }
    } else {
      float tmp[16];
      ap.ldrow16(row0 + srow, k0 + skh * 16, tmp, col0 >> 6);
      u16 tb[16];
      #pragma unroll
      for (int j = 0; j < 16; j++) tb[j] = f2bf(tmp[j]);
      *(uint4*)&Al[srow * 32 + skh * 16]     = *(const uint4*)&tb[0];
      *(uint4*)&Al[srow * 32 + skh * 16 + 8] = *(const uint4*)&tb[8];
    }
    #pragma unroll
    for (int c = 0; c < 2; c++) {
      int inst = wid * 2 + c;
      int col = col0 + inst * 16 + (lane >> 2);
      gload16(Bt + (size_t)col * 512 + k0 + (lane & 3) * 8, &Bl[inst * 512]);
    }
    __syncthreads();
    short8 afr[4], bfr[4];
    #pragma unroll
    for (int mt = 0; mt < 4; mt++)
      afr[mt] = *(const short8*)&Al[(wr * 64 + mt * 16 + lr) * 32 + lg * 8];
    #pragma unroll
    for (int ct = 0; ct < 4; ct++)
      bfr[ct] = *(const short8*)&Bl[(wc * 64 + ct * 16 + lr) * 32 + lg * 8];
    #pragma unroll
    for (int mt = 0; mt < 4; mt++)
      #pragma unroll
      for (int ct = 0; ct < 4; ct++)
        acc[mt][ct] = __builtin_amdgcn_mfma_f32_16x16x32_bf16(afr[mt], bfr[ct], acc[mt][ct], 0, 0, 0);
  }
  #pragma unroll
  for (int mt = 0; mt < 4; mt++)
    #pragma unroll
    for (int ct = 0; ct < 4; ct++)
      #pragma unroll
      for (int r = 0; r < 4; r++) {
        int rr = row0 + wr * 64 + mt * 16 + lg * 4 + r;
        if (rr < M)
          cs.st(rr, col0 + wc * 64 + ct * 16 + lr, acc[mt][ct][r]);
      }
}

// ---------- MFMA GEMM, tile 128x64 (Mix), 1-D grid, XCD-affinity ----------
template<class AP, class CS>
__global__ __launch_bounds__(256) void mgemm64(AP ap, const u16* __restrict__ Bt,
                                               CS cs, int M, int CB) {
  __shared__ __align__(16) u16 Al[128 * 32];
  __shared__ __align__(16) u16 Bl[64 * 32];
  const int tid = threadIdx.x;
  const int wid = tid >> 6, lane = tid & 63;
  const int lr = lane & 15, lg = lane >> 4;
  const int g = xcd_remap(blockIdx.x, gridDim.x);
  const int row0 = (g / CB) * 128, col0 = (g % CB) * 64;
  const int srow = tid >> 1, skh = tid & 1;
  f32x4 acc[2][4];
  #pragma unroll
  for (int i = 0; i < 2; i++)
    #pragma unroll
    for (int j = 0; j < 4; j++) acc[i][j] = (f32x4){0.f, 0.f, 0.f, 0.f};

  for (int k0 = 0; k0 < 512; k0 += 32) {
    __syncthreads();
    {
      float tmp[16];
      ap.ldrow16(row0 + srow, k0 + skh * 16, tmp, col0 >> 6);
      u16 tb[16];
      #pragma unroll
      for (int j = 0; j < 16; j++) tb[j] = f2bf(tmp[j]);
      *(uint4*)&Al[srow * 32 + skh * 16]     = *(const uint4*)&tb[0];
      *(uint4*)&Al[srow * 32 + skh * 16 + 8] = *(const uint4*)&tb[8];
    }
    {
      int col = col0 + wid * 16 + (lane >> 2);
      gload16(Bt + (size_t)col * 512 + k0 + (lane & 3) * 8, &Bl[wid * 512]);
    }
    __syncthreads();
    short8 afr[2], bfr[4];
    #pragma unroll
    for (int mt = 0; mt < 2; mt++)
      afr[mt] = *(const short8*)&Al[(wid * 32 + mt * 16 + lr) * 32 + lg * 8];
    #pragma unroll
    for (int ct = 0; ct < 4; ct++)
      bfr[ct] = *(const short8*)&Bl[(ct * 16 + lr) * 32 + lg * 8];
    #pragma unroll
    for (int mt = 0; mt < 2; mt++)
      #pragma unroll
      for (int ct = 0; ct < 4; ct++)
        acc[mt][ct] = __builtin_amdgcn_mfma_f32_16x16x32_bf16(afr[mt], bfr[ct], acc[mt][ct], 0, 0, 0);
  }
  #pragma unroll
  for (int mt = 0; mt < 2; mt++)
    #pragma unroll
    for (int ct = 0; ct < 4; ct++)
      #pragma unroll
      for (int r = 0; r < 4; r++) {
        int rr = row0 + wid * 32 + mt * 16 + lg * 4 + r;
        if (rr < M)
          cs.st(rr, col0 + ct * 16 + lr, acc[mt][ct][r]);
      }
}

// ---------- logits: k2 = xo @ Wk2 (1-D grid, XCD-affinity), epilogue q2-dot ----------
__global__ __launch_bounds__(256) void mgemm_logits(const u16* __restrict__ xo,
                                                    const u16* __restrict__ q2,
                                                    const u16* __restrict__ Wk2t,
                                                    float* __restrict__ attn2) {
  __shared__ __align__(16) u16 Al[128 * 32];
  __shared__ __align__(16) u16 Bl[128 * 32];
  const int tid = threadIdx.x;
  const int wid = tid >> 6, lane = tid & 63;
  const int lr = lane & 15, lg = lane >> 4;
  const int wr = wid >> 1, wc = wid & 1;
  const int g = xcd_remap(blockIdx.x, gridDim.x);
  const int row0 = (g >> 2) * 128, col0 = (g & 3) * 128;   // CB = 4
  f32x4 acc[4][4];
  #pragma unroll
  for (int i = 0; i < 4; i++)
    #pragma unroll
    for (int j = 0; j < 4; j++) acc[i][j] = (f32x4){0.f, 0.f, 0.f, 0.f};

  for (int k0 = 0; k0 < 512; k0 += 32) {
    __syncthreads();
    #pragma unroll
    for (int c = 0; c < 2; c++) {
      int inst = wid * 2 + c;
      int r = row0 + inst * 16 + (lane >> 2);
      int rc = r < 92000 ? r : 91999;
      gload16(xo + (size_t)rc * CC + k0 + (lane & 3) * 8, &Al[inst * 512]);
    }
    #pragma unroll
    for (int c = 0; c < 2; c++) {
      int inst = wid * 2 + c;
      int col = col0 + inst * 16 + (lane >> 2);
      gload16(Wk2t + (size_t)col * 512 + k0 + (lane & 3) * 8, &Bl[inst * 512]);
    }
    __syncthreads();
    short8 afr[4], bfr[4];
    #pragma unroll
    for (int mt = 0; mt < 4; mt++)
      afr[mt] = *(const short8*)&Al[(wr * 64 + mt * 16 + lr) * 32 + lg * 8];
    #pragma unroll
    for (int ct = 0; ct < 4; ct++)
      bfr[ct] = *(const short8*)&Bl[(wc * 64 + ct * 16 + lr) * 32 + lg * 8];
    #pragma unroll
    for (int mt = 0; mt < 4; mt++)
      #pragma unroll
      for (int ct = 0; ct < 4; ct++)
        acc[mt][ct] = __builtin_amdgcn_mfma_f32_16x16x32_bf16(afr[mt], bfr[ct], acc[mt][ct], 0, 0, 0);
  }
  const int head = (col0 >> 6) + wc;
  #pragma unroll
  for (int mt = 0; mt < 4; mt++) {
    float part[4] = {0.f, 0.f, 0.f, 0.f};
    #pragma unroll
    for (int r = 0; r < 4; r++) {
      int rr = row0 + wr * 64 + mt * 16 + lg * 4 + r;
      int rc = rr < 92000 ? rr : 91999;
      const u16* qrow = q2 + (size_t)(rc / 5) * CC + head * 64 + lr;
      #pragma unroll
      for (int ct = 0; ct < 4; ct++)
        part[r] = fmaf(acc[mt][ct][r], bf2f(qrow[ct * 16]), part[r]);
    }
    #pragma unroll
    for (int r = 0; r < 4; r++) {
      float v = part[r];
      v += __shfl_xor(v, 1);
      v += __shfl_xor(v, 2);
      v += __shfl_xor(v, 4);
      v += __shfl_xor(v, 8);
      int rr = row0 + wr * 64 + mt * 16 + lg * 4 + r;
      if (lr == 0 && rr < 92000) {
        int b = rr / (NN * FF), rem = rr - b * (NN * FF);
        int s = rem / FF, f = rem - s * FF;
        attn2[(((size_t)b * 8 + head) * NN + s) * FF + f] = v;
      }
    }
  }
}

// ---------- stage 1 (R14/R16 verbatim) ----------
__global__ __launch_bounds__(256, 2) void stage1_mfma6(const u16* __restrict__ qg,
                                                       const u16* __restrict__ kg,
                                                       const u16* __restrict__ vt,
                                                       u16* __restrict__ xo) {
  __shared__ __align__(16) u16 KF[2][16 * 512];
  __shared__ __align__(16) u16 VF[2][512 * 16];
  const int tid = threadIdx.x;
  const int wid = tid >> 6, lane = tid & 63;
  const int lr = lane & 15, lg = lane >> 4;
  const int wgid = blockIdx.x;
  const int g = (wgid & 7) * 180 + (wgid >> 3);
  const int pair = g / 72, qt = g - pair * 72;
  const int b = pair / 5, f = pair - b * 5;
  const int q0 = qt * 64 + wid * 16;

  const u16* kbase = kg + ((size_t)b * NN + f * PP) * CC;
  const u16* vpair = vt + (size_t)pair * NCHUNK * 8192;

  short8 qf[16];
  {
    int qrow = q0 + lr; if (qrow > NN - 1) qrow = NN - 1;
    const u16* qb = qg + ((size_t)b * NN + qrow) * CC + lg * 8;
    #pragma unroll
    for (int ck = 0; ck < 16; ck++) qf[ck] = *(const short8*)(qb + ck * 32);
  }
  asm volatile("s_waitcnt vmcnt(0)" ::: "memory");

  #define STAGE_KV(buf, kk0v, ckv)                                             \
    {                                                                          \
      const int kk0_ = (kk0v);                                                 \
      const u16* vcb_ = vpair + (size_t)(ckv) * 8192;                          \
      _Pragma("unroll")                                                        \
      for (int c = 0; c < 4; c++) {                                            \
        int r = wid * 4 + c;                                                   \
        int key = kk0_ + r; if (key > PP - 1) key = PP - 1;                    \
        const u16* src = kbase + (size_t)key * CC + ((lane ^ (r & 7)) * 8);    \
        gload16(src, &KF[buf][r * 512]);                                       \
      }                                                                        \
      _Pragma("unroll")                                                        \
      for (int c = 0; c < 4; c++) {                                            \
        int j = wid * 4 + c;                                                   \
        int ulin = j * 64 + lane;                                              \
        int uc = ulin ^ ((ulin >> 3) & 3);                                     \
        gload16(vcb_ + uc * 8, &VF[buf][j * 512]);                             \
      }                                                                        \
    }

  STAGE_KV(0, 0, 0)

  f32x4 acc[32];
  #pragma unroll
  for (int j = 0; j < 32; j++) acc[j] = (f32x4){0.f, 0.f, 0.f, 0.f};
  float m = 0.f, l = 0.f;

  const int vrd = (((2 * lr + (lg >> 1)) ^ (lr >> 2)) * 8) + (lg & 1) * 4;

  for (int ch = 0; ch < NCHUNK; ch++) {
    const int kk0 = ch * 16;
    const int nv = (ch == NCHUNK - 1) ? 8 : 16;
    const int cur = ch & 1, nxt = cur ^ 1;
    if (ch < NCHUNK - 1) {
      STAGE_KV(nxt, kk0 + 16, ch + 1)
      asm volatile("s_waitcnt vmcnt(8)" ::: "memory");
    } else {
      asm volatile("s_waitcnt vmcnt(0)" ::: "memory");
    }
    __builtin_amdgcn_s_barrier();
    __builtin_amdgcn_sched_barrier(0);
    const u16* Kb = &KF[cur][0];
    const u16* Vb = &VF[cur][0];
    __builtin_amdgcn_s_setprio(1);
    f32x4 sa = (f32x4){0.f, 0.f, 0.f, 0.f};
    f32x4 sb = (f32x4){0.f, 0.f, 0.f, 0.f};
    #pragma unroll
    for (int ck = 0; ck < 8; ck++) {
      int sl0 = ((lr * 64 + ck * 4 + lg) ^ (lr & 7)) * 8;
      int sl1 = ((lr * 64 + (ck + 8) * 4 + lg) ^ (lr & 7)) * 8;
      short8 k0 = *(const short8*)&Kb[sl0];
      short8 k1 = *(const short8*)&Kb[sl1];
      sa = __builtin_amdgcn_mfma_f32_16x16x32_bf16(k0, qf[ck], sa, 0, 0, 0);
      sb = __builtin_amdgcn_mfma_f32_16x16x32_bf16(k1, qf[ck + 8], sb, 0, 0, 0);
    }
    __builtin_amdgcn_s_setprio(0);
    f32x4 s0 = sa + sb;
    float pmax = -1e30f;
    #pragma unroll
    for (int r = 0; r < 4; r++) {
      s0[r] *= 0.125f;
      if (lg * 4 + r < nv) pmax = fmaxf(pmax, s0[r]);
    }
    pmax = fmaxf(pmax, __shfl_xor(pmax, 16));
    pmax = fmaxf(pmax, __shfl_xor(pmax, 32));
    if (__any(pmax - m > 8.f)) {
      float mnew = fmaxf(m, pmax);
      float rs = __expf(m - mnew);
      float rsr[4];
      #pragma unroll
      for (int r = 0; r < 4; r++) rsr[r] = __shfl(rs, lg * 4 + r);
      #pragma unroll
      for (int j = 0; j < 32; j++)
        #pragma unroll
        for (int r = 0; r < 4; r++) acc[j][r] *= rsr[r];
      l *= rs;
      m = mnew;
    }
    float p0 = (lg * 4 + 0 < nv) ? __expf(s0[0] - m) : 0.f;
    float p1 = (lg * 4 + 1 < nv) ? __expf(s0[1] - m) : 0.f;
    float p2 = (lg * 4 + 2 < nv) ? __expf(s0[2] - m) : 0.f;
    float p3 = (lg * 4 + 3 < nv) ? __expf(s0[3] - m) : 0.f;
    float psum = p0 + p1 + p2 + p3;
    psum += __shfl_xor(psum, 16);
    psum += __shfl_xor(psum, 32);
    l += psum;
    u32 pw[2] = { pack2(p0, p1), pack2(p2, p3) };
    s16x4 pf = *(const s16x4*)pw;
    __builtin_amdgcn_s_setprio(1);
    #pragma unroll
    for (int ct = 0; ct < 32; ct++) {
      s16x4 vf = *(const s16x4*)&Vb[ct * 256 + vrd];
      acc[ct] = mfma16(pf, vf, acc[ct]);
    }
    __builtin_amdgcn_s_setprio(0);
    __builtin_amdgcn_s_barrier();
  }
  asm volatile("s_nop 7\n\ts_nop 7" :::);
  float linv = 1.f / l;
  float li[4];
  #pragma unroll
  for (int r = 0; r < 4; r++) li[r] = __shfl(linv, lg * 4 + r);
  #pragma unroll
  for (int ct = 0; ct < 32; ct++) {
    #pragma unroll
    for (int r = 0; r < 4; r++) {
      int q = q0 + lg * 4 + r;
      if (q < NN)
        xo[((size_t)(b * NN + q) * FF + f) * CC + ct * 16 + lr] = f2bf(acc[ct][r] * li[r]);
    }
  }
  #undef STAGE_KV
}

// ---------- softmax over F=5, in place on attn2 ----------
__global__ __launch_bounds__(256) void softmax_f5(float* __restrict__ a) {
  int t = blockIdx.x * 256 + threadIdx.x;
  if (t >= NB * 8 * NN) return;
  float* p = a + (size_t)t * FF;
  float l0 = p[0], l1 = p[1], l2 = p[2], l3 = p[3], l4 = p[4];
  float m = fmaxf(fmaxf(fmaxf(l0, l1), fmaxf(l2, l3)), l4);
  float e0 = __expf(l0 - m), e1 = __expf(l1 - m), e2 = __expf(l2 - m),
        e3 = __expf(l3 - m), e4 = __expf(l4 - m);
  float inv = 1.f / (e0 + e1 + e2 + e3 + e4);
  p[0] = e0 * inv; p[1] = e1 * inv; p[2] = e2 * inv; p[3] = e3 * inv; p[4] = e4 * inv;
}

// ---------- sentinel ----------
__global__ void sentinel_fill(float* o) { o[threadIdx.x] = 777.0f; }

// ---------- launcher ----------
extern "C" void kernel_launch(void* const* d_in, const int* in_sizes, int n_in,
                              void* d_out, int out_size, void* d_ws, size_t ws_size,
                              hipStream_t stream) {
  const float* x     = (const float*)d_in[0];
  const float* Wqkv  = (const float*)d_in[1];
  const float* Wq2   = (const float*)d_in[2];
  const float* Wkv2  = (const float*)d_in[3];
  const float* Wproj = (const float*)d_in[4];
  const float* bproj = (const float*)d_in[5];
  float* out   = (float*)d_out;
  float* attn2 = out + (size_t)PP * NB * FF * CC;

  char* ws = (char*)d_ws;
  const size_t SZ  = (size_t)18400 * CC * 2;            // 18.8 MB
  const size_t VT2 = (size_t)20 * NCHUNK * 8192 * 2;    // 19.0 MB
  const size_t XO  = (size_t)92000 * CC * 2;            // 94.2 MB
  const size_t WT  = (size_t)(1536 + 512 + 1024 + 512) * 512 * 2;  // 3.67 MB
  const size_t NEED = 2 * SZ + VT2 + XO + WT;           // ~154.6 MB
  if (ws_size < NEED) {
    sentinel_fill<<<1, 256, 0, stream>>>(out);
    return;
  }
  u16* q    = (u16*)(ws);
  u16* k    = (u16*)(ws + SZ);
  u16* vt   = (u16*)(ws + 2 * SZ);
  u16* xo   = (u16*)(ws + 2 * SZ + VT2);
  u16* wt_qkv  = (u16*)(ws + 2 * SZ + VT2 + XO);
  u16* wt_q2   = wt_qkv + (size_t)1536 * 512;
  u16* wt_kv2  = wt_q2  + (size_t)512 * 512;
  u16* wt_proj = wt_kv2 + (size_t)1024 * 512;
  u16* q2   = (u16*)(ws);            // alias q (dead after stage1)
  u16* outp = (u16*)(ws + SZ);       // alias k (dead after stage1)
  u16* xb   = xo;                    // alias xo (free before stage1): permuted bf16 x

  // 0) weight transpose + x conversion
  wtrans<<<dim3(48, 16), 256, 0, stream>>>(Wqkv,  wt_qkv,  1536);
  wtrans<<<dim3(16, 16), 256, 0, stream>>>(Wq2,   wt_q2,   512);
  wtrans<<<dim3(32, 16), 256, 0, stream>>>(Wkv2,  wt_kv2,  1024);
  wtrans<<<dim3(16, 16), 256, 0, stream>>>(Wproj, wt_proj, 512);
  xcvt<<<4600, 256, 0, stream>>>(x, xb);

  // 1) QKV projection (full DMA; v written chunk-blocked-16 transposed)
  {
    AProvBF ap{xb, 18400}; CSinkQKV cs{q, k, vt};
    mgemm128<<<1728, 256, 0, stream>>>(ap, wt_qkv, cs, 18400, 12);
  }
  // 2) stage-1 space attention -> xo (overwrites xb, which is dead now)
  stage1_mfma6<<<1440, 256, 0, stream>>>(q, k, vt, xo);
  // 3) q2 = diag(xo) @ W_q2 * scale
  {
    AProvDiag ap{xo}; CSinkQ2 cs{q2};
    mgemm128<<<576, 256, 0, stream>>>(ap, wt_q2, cs, 18400, 4);
  }
  // 4) fused k2-GEMM + q2 dot -> raw logits
  mgemm_logits<<<2876, 256, 0, stream>>>(xo, q2, wt_kv2, attn2);
  // 5) softmax over F in place
  softmax_f5<<<(NB * 8 * NN + 255) / 256, 256, 0, stream>>>(attn2);
  // 6) fused mix + W_v2 -> out_pre (VALU-A + DMA-B); head from col block
  {
    AProvMix ap{xo, attn2}; CSinkBF512 cs{outp};
    mgemm64<<<1152, 256, 0, stream>>>(ap, wt_kv2 + (size_t)512 * 512, cs, 18400, 8);
  }
  // 7) final projection + bias + permute
  {
    AProvBF ap{outp, 18400}; CSinkProj cs{out, bproj};
    mgemm128<<<576, 256, 0, stream>>>(ap, wt_proj, cs, 18400, 4);
  }
}